// Round 1
// baseline (702.288 us; speedup 1.0000x reference)
//
#include <hip/hip_runtime.h>
#include <stdint.h>

#define S_LEN 8192
#define DIM   1024
#define NH    16
#define HD    64
#define WIN   1024
#define GTOK  256
#define QKV_STRIDE (3 * DIM)

typedef __attribute__((ext_vector_type(8))) short bf16x8;
typedef __attribute__((ext_vector_type(4))) float f32x4;
typedef unsigned short u16;

__device__ __forceinline__ u16 f2bf(float f) {
  union { float f; uint32_t u; } v; v.f = f;
  uint32_t r = v.u + 0x7fffu + ((v.u >> 16) & 1u);
  return (u16)(r >> 16);
}

__device__ __forceinline__ void gload_lds16(const void* g, void* l) {
  __builtin_amdgcn_global_load_lds((const __attribute__((address_space(1))) void*)g,
                                   (__attribute__((address_space(3))) void*)l, 16, 0, 0);
}

// ---------------- RMSNorm + scorer ----------------
__global__ __launch_bounds__(256) void rmsnorm_score_kernel(
    const float* __restrict__ x, const float* __restrict__ nw,
    const float* __restrict__ sw, const float* __restrict__ sb,
    u16* __restrict__ h, float* __restrict__ scores) {
  int row = blockIdx.x, tid = threadIdx.x;
  const float4* xr = (const float4*)(x + (size_t)row * DIM);
  float4 v = xr[tid];
  float ss = v.x * v.x + v.y * v.y + v.z * v.z + v.w * v.w;
#pragma unroll
  for (int o = 32; o >= 1; o >>= 1) ss += __shfl_xor(ss, o);
  __shared__ float red[4], red2[4];
  int wv = tid >> 6;
  if ((tid & 63) == 0) red[wv] = ss;
  __syncthreads();
  ss = red[0] + red[1] + red[2] + red[3];
  float rn = rsqrtf(ss * (1.0f / DIM) + 1e-6f);
  float4 w4 = ((const float4*)nw)[tid];
  float h0 = v.x * rn * w4.x, h1 = v.y * rn * w4.y;
  float h2 = v.z * rn * w4.z, h3 = v.w * rn * w4.w;
  uint64_t pack = (uint64_t)f2bf(h0) | ((uint64_t)f2bf(h1) << 16) |
                  ((uint64_t)f2bf(h2) << 32) | ((uint64_t)f2bf(h3) << 48);
  *(uint64_t*)(h + (size_t)row * DIM + tid * 4) = pack;
  float4 s4 = ((const float4*)sw)[tid];
  float sc = h0 * s4.x + h1 * s4.y + h2 * s4.z + h3 * s4.w;
#pragma unroll
  for (int o = 32; o >= 1; o >>= 1) sc += __shfl_xor(sc, o);
  if ((tid & 63) == 0) red2[wv] = sc;
  __syncthreads();
  if (tid == 0) scores[row] = red2[0] + red2[1] + red2[2] + red2[3] + sb[0];
}

// ---------------- weight transpose + bf16 convert ----------------
__global__ __launch_bounds__(256) void transpose_w_kernel(
    const float* __restrict__ wq, const float* __restrict__ wk,
    const float* __restrict__ wv, const float* __restrict__ wo,
    u16* __restrict__ wqkvT, u16* __restrict__ woutT) {
  __shared__ float tile[32][33];
  int z = blockIdx.z;
  const float* src = (z == 0) ? wq : (z == 1) ? wk : (z == 2) ? wv : wo;
  u16* dst = (z < 3) ? (wqkvT + (size_t)z * DIM * DIM) : woutT;
  int tx = threadIdx.x, ty = threadIdx.y;  // 32 x 8
  int n0 = blockIdx.x * 32, k0 = blockIdx.y * 32;
#pragma unroll
  for (int i = 0; i < 4; i++)
    tile[ty + i * 8][tx] = src[(size_t)(k0 + ty + i * 8) * DIM + n0 + tx];
  __syncthreads();
#pragma unroll
  for (int i = 0; i < 4; i++)
    dst[(size_t)(n0 + ty + i * 8) * DIM + k0 + tx] = f2bf(tile[tx][ty + i * 8]);
}

// ---------------- exact top-G by rank counting ----------------
__global__ __launch_bounds__(1024) void topk_kernel(const float* __restrict__ scores,
                                                    int* __restrict__ gidx) {
  __shared__ float sc[S_LEN];
  for (int i = threadIdx.x; i < S_LEN; i += 1024) sc[i] = scores[i];
  __syncthreads();
  int i = blockIdx.x * 1024 + threadIdx.x;
  float my = sc[i];
  int cnt = 0;
  const float4* s4 = (const float4*)sc;
  for (int j = 0; j < S_LEN / 4; j++) {
    float4 v = s4[j];
    int b = j * 4;
    cnt += (v.x > my) || (v.x == my && (b + 0) < i);
    cnt += (v.y > my) || (v.y == my && (b + 1) < i);
    cnt += (v.z > my) || (v.z == my && (b + 2) < i);
    cnt += (v.w > my) || (v.w == my && (b + 3) < i);
  }
  if (cnt < GTOK) gidx[cnt] = i;
}

// ---------------- gather top-G K/V rows ----------------
__global__ __launch_bounds__(128) void gather_kernel(
    const u16* __restrict__ qkv, const int* __restrict__ gidx,
    u16* __restrict__ kg, u16* __restrict__ vg) {
  int g = blockIdx.x, t = threadIdx.x;
  size_t src = (size_t)gidx[g] * QKV_STRIDE;
  *(bf16x8*)(kg + (size_t)g * DIM + t * 8) = *(const bf16x8*)(qkv + src + DIM + t * 8);
  *(bf16x8*)(vg + (size_t)g * DIM + t * 8) = *(const bf16x8*)(qkv + src + 2 * DIM + t * 8);
}

// ---------------- GEMM: C[m][n] = sum_k A[m][k]*B[n][k] (both row-major, K contig) ----------------
// 128x128 tile, BK=64, 4 waves, 16x16x32 bf16 MFMA. RESID=1: fp32 out = X + acc.
template <int RESID>
__global__ __launch_bounds__(256) void gemm_bt_kernel(
    const u16* __restrict__ A, const u16* __restrict__ B,
    u16* __restrict__ Cb, float* __restrict__ Cf, const float* __restrict__ X,
    int M, int N, int K) {
  __shared__ u16 aT[128 * 64];
  __shared__ u16 bT[128 * 64];
  int tid = threadIdx.x;
  int wave = tid >> 6, lane = tid & 63;
  int l15 = lane & 15, l4 = lane >> 4;
  int wr = (wave >> 1) * 64, wc = (wave & 1) * 64;
  int mbase = blockIdx.x * 128, nbase = blockIdx.y * 128;
  f32x4 acc[4][4] = {};
  for (int kt = 0; kt < K; kt += 64) {
#pragma unroll
    for (int c = 0; c < 4; c++) {
      int chunk = wave * 4 + c;
      int row = chunk * 8 + (lane >> 3);
      int col = kt + (lane & 7) * 8;
      gload_lds16(A + (size_t)(mbase + row) * K + col, aT + chunk * 512);
      gload_lds16(B + (size_t)(nbase + row) * K + col, bT + chunk * 512);
    }
    __syncthreads();
#pragma unroll
    for (int kk = 0; kk < 2; kk++) {
      bf16x8 af[4], bfr[4];
#pragma unroll
      for (int i = 0; i < 4; i++) {
        af[i]  = *(const bf16x8*)(aT + (wr + i * 16 + l15) * 64 + kk * 32 + l4 * 8);
        bfr[i] = *(const bf16x8*)(bT + (wc + i * 16 + l15) * 64 + kk * 32 + l4 * 8);
      }
#pragma unroll
      for (int i = 0; i < 4; i++)
#pragma unroll
        for (int j = 0; j < 4; j++)
          acc[i][j] = __builtin_amdgcn_mfma_f32_16x16x32_bf16(af[i], bfr[j], acc[i][j], 0, 0, 0);
    }
    __syncthreads();
  }
#pragma unroll
  for (int i = 0; i < 4; i++) {
#pragma unroll
    for (int j = 0; j < 4; j++) {
#pragma unroll
      for (int r = 0; r < 4; r++) {
        int row = mbase + wr + i * 16 + l4 * 4 + r;
        int col = nbase + wc + j * 16 + l15;
        float v = acc[i][j][r];
        if (RESID) Cf[(size_t)row * N + col] = X[(size_t)row * N + col] + v;
        else       Cb[(size_t)row * N + col] = f2bf(v);
      }
    }
  }
}

// ---------------- fused flash attention (local windows + global top-G, joint softmax) ----------------
__global__ __launch_bounds__(256) void attn_kernel(
    const u16* __restrict__ qkv, const u16* __restrict__ kg,
    const u16* __restrict__ vg, const int* __restrict__ gidx,
    u16* __restrict__ o) {
  __shared__ u16 kLds[32 * 72];      // [key][d], stride 72 (pad 8)
  __shared__ u16 vtLds[64 * 40];     // [d][key], stride 40 (pad 8)
  __shared__ u16 pLds[4][16 * 40];   // per-wave [q][key], stride 40
  __shared__ int gposLds[32];
  int qblk = blockIdx.x, h = blockIdx.y;
  int tid = threadIdx.x, wave = tid >> 6, lane = tid & 63;
  int qbase = qblk * 64;
  int wbase = qbase & ~(WIN - 1);
  int hoff = h * HD;
  int l15 = lane & 15, l4 = lane >> 4;

  const u16* qrow = qkv + (size_t)(qbase + wave * 16 + l15) * QKV_STRIDE + hoff;
  bf16x8 aq0 = *(const bf16x8*)(qrow + l4 * 8);
  bf16x8 aq1 = *(const bf16x8*)(qrow + 32 + l4 * 8);

  f32x4 acc[4] = {};
  float mr[4] = {-1e30f, -1e30f, -1e30f, -1e30f};
  float lr[4] = {0.f, 0.f, 0.f, 0.f};
  int qpos[4];
#pragma unroll
  for (int r = 0; r < 4; r++) qpos[r] = qbase + wave * 16 + l4 * 4 + r;

  int qoff = qbase - wbase;
  int nLocal = qoff / 32 + 2;
  int nTiles = nLocal + GTOK / 32;
  int skey = tid >> 3, sch = tid & 7;

  for (int t = 0; t < nTiles; t++) {
    bool isLocal = (t < nLocal);
    {  // stage K tile + transposed V tile (+ global positions)
      const u16 *ks, *vs;
      if (isLocal) {
        int krow = wbase + t * 32 + skey;
        ks = qkv + (size_t)krow * QKV_STRIDE + DIM + hoff;
        vs = qkv + (size_t)krow * QKV_STRIDE + 2 * DIM + hoff;
      } else {
        int gi = (t - nLocal) * 32 + skey;
        ks = kg + (size_t)gi * DIM + hoff;
        vs = vg + (size_t)gi * DIM + hoff;
        if (tid < 32) gposLds[tid] = gidx[(t - nLocal) * 32 + tid];
      }
      *(bf16x8*)(kLds + skey * 72 + sch * 8) = *(const bf16x8*)(ks + sch * 8);
      bf16x8 vv = *(const bf16x8*)(vs + sch * 8);
#pragma unroll
      for (int j = 0; j < 8; j++) vtLds[(sch * 8 + j) * 40 + skey] = (u16)vv[j];
    }
    __syncthreads();
    {  // compute
      bf16x8 k0a = *(const bf16x8*)(kLds + l15 * 72 + l4 * 8);
      bf16x8 k0b = *(const bf16x8*)(kLds + l15 * 72 + 32 + l4 * 8);
      bf16x8 k1a = *(const bf16x8*)(kLds + (16 + l15) * 72 + l4 * 8);
      bf16x8 k1b = *(const bf16x8*)(kLds + (16 + l15) * 72 + 32 + l4 * 8);
      f32x4 s0 = {}, s1 = {};
      s0 = __builtin_amdgcn_mfma_f32_16x16x32_bf16(aq0, k0a, s0, 0, 0, 0);
      s0 = __builtin_amdgcn_mfma_f32_16x16x32_bf16(aq1, k0b, s0, 0, 0, 0);
      s1 = __builtin_amdgcn_mfma_f32_16x16x32_bf16(aq0, k1a, s1, 0, 0, 0);
      s1 = __builtin_amdgcn_mfma_f32_16x16x32_bf16(aq1, k1b, s1, 0, 0, 0);
      int kp0, kp1;
      if (isLocal) { kp0 = wbase + t * 32 + l15; kp1 = kp0 + 16; }
      else         { kp0 = gposLds[l15]; kp1 = gposLds[16 + l15]; }
      const float scale = 0.125f;  // 1/sqrt(64)
      float v0[4], v1[4], rm[4], al[4], p0[4], p1[4], rs[4];
#pragma unroll
      for (int r = 0; r < 4; r++) {
        v0[r] = (kp0 <= qpos[r]) ? s0[r] * scale : -1e30f;
        v1[r] = (kp1 <= qpos[r]) ? s1[r] * scale : -1e30f;
        rm[r] = fmaxf(v0[r], v1[r]);
      }
#pragma unroll
      for (int off = 1; off < 16; off <<= 1)
#pragma unroll
        for (int r = 0; r < 4; r++) rm[r] = fmaxf(rm[r], __shfl_xor(rm[r], off));
#pragma unroll
      for (int r = 0; r < 4; r++) {
        float mn = fmaxf(mr[r], rm[r]);
        al[r] = __expf(mr[r] - mn);
        p0[r] = __expf(v0[r] - mn);
        p1[r] = __expf(v1[r] - mn);
        mr[r] = mn;
        rs[r] = p0[r] + p1[r];
      }
#pragma unroll
      for (int off = 1; off < 16; off <<= 1)
#pragma unroll
        for (int r = 0; r < 4; r++) rs[r] += __shfl_xor(rs[r], off);
#pragma unroll
      for (int r = 0; r < 4; r++) lr[r] = lr[r] * al[r] + rs[r];
#pragma unroll
      for (int df = 0; df < 4; df++) {
        f32x4 a = acc[df];
        a[0] *= al[0]; a[1] *= al[1]; a[2] *= al[2]; a[3] *= al[3];
        acc[df] = a;
      }
      u16* pw = pLds[wave];
#pragma unroll
      for (int r = 0; r < 4; r++) {
        pw[(l4 * 4 + r) * 40 + l15] = f2bf(p0[r]);
        pw[(l4 * 4 + r) * 40 + 16 + l15] = f2bf(p1[r]);
      }
      bf16x8 pa = *(const bf16x8*)(pw + l15 * 40 + l4 * 8);
#pragma unroll
      for (int df = 0; df < 4; df++) {
        bf16x8 bv = *(const bf16x8*)(vtLds + (df * 16 + l15) * 40 + l4 * 8);
        acc[df] = __builtin_amdgcn_mfma_f32_16x16x32_bf16(pa, bv, acc[df], 0, 0, 0);
      }
    }
    __syncthreads();
  }
#pragma unroll
  for (int df = 0; df < 4; df++)
#pragma unroll
    for (int r = 0; r < 4; r++)
      o[(size_t)qpos[r] * DIM + hoff + df * 16 + l15] = f2bf(acc[df][r] / lr[r]);
}

// ---------------- launch ----------------
extern "C" void kernel_launch(void* const* d_in, const int* in_sizes, int n_in,
                              void* d_out, int out_size, void* d_ws, size_t ws_size,
                              hipStream_t stream) {
  const float* x  = (const float*)d_in[0];
  const float* nw = (const float*)d_in[1];
  const float* wq = (const float*)d_in[2];
  const float* wk = (const float*)d_in[3];
  const float* wv = (const float*)d_in[4];
  const float* wo = (const float*)d_in[5];
  const float* sw = (const float*)d_in[6];
  const float* sb = (const float*)d_in[7];
  float* out = (float*)d_out;

  char* ws = (char*)d_ws;
  size_t off = 0;
  auto alloc = [&](size_t b) {
    char* p = ws + off;
    off = (off + b + 255) & ~(size_t)255;
    return p;
  };
  u16*   h      = (u16*)alloc((size_t)S_LEN * DIM * 2);        // 16 MB
  u16*   wqkvT  = (u16*)alloc((size_t)3 * DIM * DIM * 2);      // 6 MB
  u16*   woutT  = (u16*)alloc((size_t)DIM * DIM * 2);          // 2 MB
  u16*   qkv    = (u16*)alloc((size_t)S_LEN * 3 * DIM * 2);    // 48 MB
  u16*   obuf   = (u16*)alloc((size_t)S_LEN * DIM * 2);        // 16 MB
  float* scores = (float*)alloc((size_t)S_LEN * 4);
  int*   gidx   = (int*)alloc((size_t)GTOK * 4);
  u16*   kgbuf  = (u16*)alloc((size_t)GTOK * DIM * 2);
  u16*   vgbuf  = (u16*)alloc((size_t)GTOK * DIM * 2);

  transpose_w_kernel<<<dim3(32, 32, 4), dim3(32, 8), 0, stream>>>(wq, wk, wv, wo, wqkvT, woutT);
  rmsnorm_score_kernel<<<dim3(S_LEN), dim3(256), 0, stream>>>(x, nw, sw, sb, h, scores);
  topk_kernel<<<dim3(8), dim3(1024), 0, stream>>>(scores, gidx);
  gemm_bt_kernel<0><<<dim3(64, 24), dim3(256), 0, stream>>>(h, wqkvT, qkv, nullptr, nullptr,
                                                            S_LEN, 3 * DIM, DIM);
  gather_kernel<<<dim3(GTOK), dim3(128), 0, stream>>>(qkv, gidx, kgbuf, vgbuf);
  attn_kernel<<<dim3(S_LEN / 64, NH), dim3(256), 0, stream>>>(qkv, kgbuf, vgbuf, gidx, obuf);
  gemm_bt_kernel<1><<<dim3(64, 8), dim3(256), 0, stream>>>(obuf, woutT, nullptr, out, x,
                                                           S_LEN, DIM, DIM);
}

// Round 2
// 420.198 us; speedup vs baseline: 1.6713x; 1.6713x over previous
//
#include <hip/hip_runtime.h>
#include <stdint.h>

#define S_LEN 8192
#define DIM   1024
#define NH    16
#define HD    64
#define WIN   1024
#define GTOK  256
#define QKV_STRIDE (3 * DIM)

typedef __attribute__((ext_vector_type(8))) short bf16x8;
typedef __attribute__((ext_vector_type(4))) float f32x4;
typedef unsigned short u16;

__device__ __forceinline__ u16 f2bf(float f) {
  union { float f; uint32_t u; } v; v.f = f;
  uint32_t r = v.u + 0x7fffu + ((v.u >> 16) & 1u);
  return (u16)(r >> 16);
}

__device__ __forceinline__ void gload_lds16(const void* g, void* l) {
  __builtin_amdgcn_global_load_lds((const __attribute__((address_space(1))) void*)g,
                                   (__attribute__((address_space(3))) void*)l, 16, 0, 0);
}

// ---------------- RMSNorm + scorer ----------------
__global__ __launch_bounds__(256) void rmsnorm_score_kernel(
    const float* __restrict__ x, const float* __restrict__ nw,
    const float* __restrict__ sw, const float* __restrict__ sb,
    u16* __restrict__ h, float* __restrict__ scores) {
  int row = blockIdx.x, tid = threadIdx.x;
  const float4* xr = (const float4*)(x + (size_t)row * DIM);
  float4 v = xr[tid];
  float ss = v.x * v.x + v.y * v.y + v.z * v.z + v.w * v.w;
#pragma unroll
  for (int o = 32; o >= 1; o >>= 1) ss += __shfl_xor(ss, o);
  __shared__ float red[4], red2[4];
  int wv = tid >> 6;
  if ((tid & 63) == 0) red[wv] = ss;
  __syncthreads();
  ss = red[0] + red[1] + red[2] + red[3];
  float rn = rsqrtf(ss * (1.0f / DIM) + 1e-6f);
  float4 w4 = ((const float4*)nw)[tid];
  float h0 = v.x * rn * w4.x, h1 = v.y * rn * w4.y;
  float h2 = v.z * rn * w4.z, h3 = v.w * rn * w4.w;
  uint64_t pack = (uint64_t)f2bf(h0) | ((uint64_t)f2bf(h1) << 16) |
                  ((uint64_t)f2bf(h2) << 32) | ((uint64_t)f2bf(h3) << 48);
  *(uint64_t*)(h + (size_t)row * DIM + tid * 4) = pack;
  float4 s4 = ((const float4*)sw)[tid];
  float sc = h0 * s4.x + h1 * s4.y + h2 * s4.z + h3 * s4.w;
#pragma unroll
  for (int o = 32; o >= 1; o >>= 1) sc += __shfl_xor(sc, o);
  if ((tid & 63) == 0) red2[wv] = sc;
  __syncthreads();
  if (tid == 0) scores[row] = red2[0] + red2[1] + red2[2] + red2[3] + sb[0];
}

// ---------------- weight transpose + bf16 convert ----------------
__global__ __launch_bounds__(256) void transpose_w_kernel(
    const float* __restrict__ wq, const float* __restrict__ wk,
    const float* __restrict__ wv, const float* __restrict__ wo,
    u16* __restrict__ wqkvT, u16* __restrict__ woutT) {
  __shared__ float tile[32][33];
  int z = blockIdx.z;
  const float* src = (z == 0) ? wq : (z == 1) ? wk : (z == 2) ? wv : wo;
  u16* dst = (z < 3) ? (wqkvT + (size_t)z * DIM * DIM) : woutT;
  int tx = threadIdx.x, ty = threadIdx.y;  // 32 x 8
  int n0 = blockIdx.x * 32, k0 = blockIdx.y * 32;
#pragma unroll
  for (int i = 0; i < 4; i++)
    tile[ty + i * 8][tx] = src[(size_t)(k0 + ty + i * 8) * DIM + n0 + tx];
  __syncthreads();
#pragma unroll
  for (int i = 0; i < 4; i++)
    dst[(size_t)(n0 + ty + i * 8) * DIM + k0 + tx] = f2bf(tile[tx][ty + i * 8]);
}

// ---------------- exact top-G by distributed rank counting ----------------
__global__ __launch_bounds__(256) void topk_init_kernel(int* __restrict__ cnt) {
  cnt[blockIdx.x * 256 + threadIdx.x] = 0;
}

// grid (32 i-blocks, 8 j-tiles) x 256 threads; each thread: one candidate i,
// counts rank contributions from one 1024-wide j-tile staged in LDS.
__global__ __launch_bounds__(256) void topk_count_kernel(
    const float* __restrict__ scores, int* __restrict__ cnt) {
  __shared__ float sj[1024];
  int jbase = blockIdx.y * 1024;
  for (int t = threadIdx.x; t < 1024; t += 256) sj[t] = scores[jbase + t];
  __syncthreads();
  int i = blockIdx.x * 256 + threadIdx.x;
  float my = scores[i];
  int c = 0;
  const float4* s4 = (const float4*)sj;
#pragma unroll 4
  for (int j = 0; j < 256; j++) {
    float4 v = s4[j];
    int b = jbase + j * 4;
    c += (v.x > my) || (v.x == my && (b + 0) < i);
    c += (v.y > my) || (v.y == my && (b + 1) < i);
    c += (v.z > my) || (v.z == my && (b + 2) < i);
    c += (v.w > my) || (v.w == my && (b + 3) < i);
  }
  if (c) atomicAdd(&cnt[i], c);
}

__global__ __launch_bounds__(256) void topk_scatter_kernel(
    const int* __restrict__ cnt, int* __restrict__ gidx) {
  int i = blockIdx.x * 256 + threadIdx.x;
  int c = cnt[i];
  if (c < GTOK) gidx[c] = i;
}

// ---------------- gather top-G K/V rows ----------------
__global__ __launch_bounds__(128) void gather_kernel(
    const u16* __restrict__ qkv, const int* __restrict__ gidx,
    u16* __restrict__ kg, u16* __restrict__ vg) {
  int g = blockIdx.x, t = threadIdx.x;
  size_t src = (size_t)gidx[g] * QKV_STRIDE;
  *(bf16x8*)(kg + (size_t)g * DIM + t * 8) = *(const bf16x8*)(qkv + src + DIM + t * 8);
  *(bf16x8*)(vg + (size_t)g * DIM + t * 8) = *(const bf16x8*)(qkv + src + 2 * DIM + t * 8);
}

// ---------------- GEMM: C[m][n] = sum_k A[m][k]*B[n][k] (both row-major, K contig) ----------------
// 128x128 tile, BK=64, 4 waves, 16x16x32 bf16 MFMA. RESID=1: fp32 out = X + acc.
template <int RESID>
__global__ __launch_bounds__(256) void gemm_bt_kernel(
    const u16* __restrict__ A, const u16* __restrict__ B,
    u16* __restrict__ Cb, float* __restrict__ Cf, const float* __restrict__ X,
    int M, int N, int K) {
  __shared__ u16 aT[128 * 64];
  __shared__ u16 bT[128 * 64];
  int tid = threadIdx.x;
  int wave = tid >> 6, lane = tid & 63;
  int l15 = lane & 15, l4 = lane >> 4;
  int wr = (wave >> 1) * 64, wc = (wave & 1) * 64;
  int mbase = blockIdx.x * 128, nbase = blockIdx.y * 128;
  f32x4 acc[4][4] = {};
  for (int kt = 0; kt < K; kt += 64) {
#pragma unroll
    for (int c = 0; c < 4; c++) {
      int chunk = wave * 4 + c;
      int row = chunk * 8 + (lane >> 3);
      int col = kt + (lane & 7) * 8;
      gload_lds16(A + (size_t)(mbase + row) * K + col, aT + chunk * 512);
      gload_lds16(B + (size_t)(nbase + row) * K + col, bT + chunk * 512);
    }
    __syncthreads();
#pragma unroll
    for (int kk = 0; kk < 2; kk++) {
      bf16x8 af[4], bfr[4];
#pragma unroll
      for (int i = 0; i < 4; i++) {
        af[i]  = *(const bf16x8*)(aT + (wr + i * 16 + l15) * 64 + kk * 32 + l4 * 8);
        bfr[i] = *(const bf16x8*)(bT + (wc + i * 16 + l15) * 64 + kk * 32 + l4 * 8);
      }
#pragma unroll
      for (int i = 0; i < 4; i++)
#pragma unroll
        for (int j = 0; j < 4; j++)
          acc[i][j] = __builtin_amdgcn_mfma_f32_16x16x32_bf16(af[i], bfr[j], acc[i][j], 0, 0, 0);
    }
    __syncthreads();
  }
#pragma unroll
  for (int i = 0; i < 4; i++) {
#pragma unroll
    for (int j = 0; j < 4; j++) {
#pragma unroll
      for (int r = 0; r < 4; r++) {
        int row = mbase + wr + i * 16 + l4 * 4 + r;
        int col = nbase + wc + j * 16 + l15;
        float v = acc[i][j][r];
        if (RESID) Cf[(size_t)row * N + col] = X[(size_t)row * N + col] + v;
        else       Cb[(size_t)row * N + col] = f2bf(v);
      }
    }
  }
}

// ---------------- fused flash attention (local windows + global top-G, joint softmax) ----------------
__global__ __launch_bounds__(256) void attn_kernel(
    const u16* __restrict__ qkv, const u16* __restrict__ kg,
    const u16* __restrict__ vg, const int* __restrict__ gidx,
    u16* __restrict__ o) {
  __shared__ u16 kLds[32 * 72];      // [key][d], stride 72 (pad 8)
  __shared__ u16 vtLds[64 * 40];     // [d][key], stride 40 (pad 8)
  __shared__ u16 pLds[4][16 * 40];   // per-wave [q][key], stride 40
  __shared__ int gposLds[32];
  int qblk = blockIdx.x, h = blockIdx.y;
  int tid = threadIdx.x, wave = tid >> 6, lane = tid & 63;
  int qbase = qblk * 64;
  int wbase = qbase & ~(WIN - 1);
  int hoff = h * HD;
  int l15 = lane & 15, l4 = lane >> 4;

  const u16* qrow = qkv + (size_t)(qbase + wave * 16 + l15) * QKV_STRIDE + hoff;
  bf16x8 aq0 = *(const bf16x8*)(qrow + l4 * 8);
  bf16x8 aq1 = *(const bf16x8*)(qrow + 32 + l4 * 8);

  f32x4 acc[4] = {};
  float mr[4] = {-1e30f, -1e30f, -1e30f, -1e30f};
  float lr[4] = {0.f, 0.f, 0.f, 0.f};
  int qpos[4];
#pragma unroll
  for (int r = 0; r < 4; r++) qpos[r] = qbase + wave * 16 + l4 * 4 + r;

  int qoff = qbase - wbase;
  int nLocal = qoff / 32 + 2;
  int nTiles = nLocal + GTOK / 32;
  int skey = tid >> 3, sch = tid & 7;

  for (int t = 0; t < nTiles; t++) {
    bool isLocal = (t < nLocal);
    {  // stage K tile + transposed V tile (+ global positions)
      const u16 *ks, *vs;
      if (isLocal) {
        int krow = wbase + t * 32 + skey;
        ks = qkv + (size_t)krow * QKV_STRIDE + DIM + hoff;
        vs = qkv + (size_t)krow * QKV_STRIDE + 2 * DIM + hoff;
      } else {
        int gi = (t - nLocal) * 32 + skey;
        ks = kg + (size_t)gi * DIM + hoff;
        vs = vg + (size_t)gi * DIM + hoff;
        if (tid < 32) gposLds[tid] = gidx[(t - nLocal) * 32 + tid];
      }
      *(bf16x8*)(kLds + skey * 72 + sch * 8) = *(const bf16x8*)(ks + sch * 8);
      bf16x8 vv = *(const bf16x8*)(vs + sch * 8);
#pragma unroll
      for (int j = 0; j < 8; j++) vtLds[(sch * 8 + j) * 40 + skey] = (u16)vv[j];
    }
    __syncthreads();
    {  // compute
      bf16x8 k0a = *(const bf16x8*)(kLds + l15 * 72 + l4 * 8);
      bf16x8 k0b = *(const bf16x8*)(kLds + l15 * 72 + 32 + l4 * 8);
      bf16x8 k1a = *(const bf16x8*)(kLds + (16 + l15) * 72 + l4 * 8);
      bf16x8 k1b = *(const bf16x8*)(kLds + (16 + l15) * 72 + 32 + l4 * 8);
      f32x4 s0 = {}, s1 = {};
      s0 = __builtin_amdgcn_mfma_f32_16x16x32_bf16(aq0, k0a, s0, 0, 0, 0);
      s0 = __builtin_amdgcn_mfma_f32_16x16x32_bf16(aq1, k0b, s0, 0, 0, 0);
      s1 = __builtin_amdgcn_mfma_f32_16x16x32_bf16(aq0, k1a, s1, 0, 0, 0);
      s1 = __builtin_amdgcn_mfma_f32_16x16x32_bf16(aq1, k1b, s1, 0, 0, 0);
      int kp0, kp1;
      if (isLocal) { kp0 = wbase + t * 32 + l15; kp1 = kp0 + 16; }
      else         { kp0 = gposLds[l15]; kp1 = gposLds[16 + l15]; }
      const float scale = 0.125f;  // 1/sqrt(64)
      float v0[4], v1[4], rm[4], al[4], p0[4], p1[4], rs[4];
#pragma unroll
      for (int r = 0; r < 4; r++) {
        v0[r] = (kp0 <= qpos[r]) ? s0[r] * scale : -1e30f;
        v1[r] = (kp1 <= qpos[r]) ? s1[r] * scale : -1e30f;
        rm[r] = fmaxf(v0[r], v1[r]);
      }
#pragma unroll
      for (int off = 1; off < 16; off <<= 1)
#pragma unroll
        for (int r = 0; r < 4; r++) rm[r] = fmaxf(rm[r], __shfl_xor(rm[r], off));
#pragma unroll
      for (int r = 0; r < 4; r++) {
        float mn = fmaxf(mr[r], rm[r]);
        al[r] = __expf(mr[r] - mn);
        p0[r] = __expf(v0[r] - mn);
        p1[r] = __expf(v1[r] - mn);
        mr[r] = mn;
        rs[r] = p0[r] + p1[r];
      }
#pragma unroll
      for (int off = 1; off < 16; off <<= 1)
#pragma unroll
        for (int r = 0; r < 4; r++) rs[r] += __shfl_xor(rs[r], off);
#pragma unroll
      for (int r = 0; r < 4; r++) lr[r] = lr[r] * al[r] + rs[r];
#pragma unroll
      for (int df = 0; df < 4; df++) {
        f32x4 a = acc[df];
        a[0] *= al[0]; a[1] *= al[1]; a[2] *= al[2]; a[3] *= al[3];
        acc[df] = a;
      }
      u16* pw = pLds[wave];
#pragma unroll
      for (int r = 0; r < 4; r++) {
        pw[(l4 * 4 + r) * 40 + l15] = f2bf(p0[r]);
        pw[(l4 * 4 + r) * 40 + 16 + l15] = f2bf(p1[r]);
      }
      bf16x8 pa = *(const bf16x8*)(pw + l15 * 40 + l4 * 8);
#pragma unroll
      for (int df = 0; df < 4; df++) {
        bf16x8 bv = *(const bf16x8*)(vtLds + (df * 16 + l15) * 40 + l4 * 8);
        acc[df] = __builtin_amdgcn_mfma_f32_16x16x32_bf16(pa, bv, acc[df], 0, 0, 0);
      }
    }
    __syncthreads();
  }
#pragma unroll
  for (int df = 0; df < 4; df++)
#pragma unroll
    for (int r = 0; r < 4; r++)
      o[(size_t)qpos[r] * DIM + hoff + df * 16 + l15] = f2bf(acc[df][r] / lr[r]);
}

// ---------------- launch ----------------
extern "C" void kernel_launch(void* const* d_in, const int* in_sizes, int n_in,
                              void* d_out, int out_size, void* d_ws, size_t ws_size,
                              hipStream_t stream) {
  const float* x  = (const float*)d_in[0];
  const float* nw = (const float*)d_in[1];
  const float* wq = (const float*)d_in[2];
  const float* wk = (const float*)d_in[3];
  const float* wv = (const float*)d_in[4];
  const float* wo = (const float*)d_in[5];
  const float* sw = (const float*)d_in[6];
  const float* sb = (const float*)d_in[7];
  float* out = (float*)d_out;

  char* ws = (char*)d_ws;
  size_t off = 0;
  auto alloc = [&](size_t b) {
    char* p = ws + off;
    off = (off + b + 255) & ~(size_t)255;
    return p;
  };
  u16*   h      = (u16*)alloc((size_t)S_LEN * DIM * 2);        // 16 MB
  u16*   wqkvT  = (u16*)alloc((size_t)3 * DIM * DIM * 2);      // 6 MB
  u16*   woutT  = (u16*)alloc((size_t)DIM * DIM * 2);          // 2 MB
  u16*   qkv    = (u16*)alloc((size_t)S_LEN * 3 * DIM * 2);    // 48 MB
  u16*   obuf   = (u16*)alloc((size_t)S_LEN * DIM * 2);        // 16 MB
  float* scores = (float*)alloc((size_t)S_LEN * 4);
  int*   gidx   = (int*)alloc((size_t)GTOK * 4);
  int*   cnt    = (int*)alloc((size_t)S_LEN * 4);
  u16*   kgbuf  = (u16*)alloc((size_t)GTOK * DIM * 2);
  u16*   vgbuf  = (u16*)alloc((size_t)GTOK * DIM * 2);

  transpose_w_kernel<<<dim3(32, 32, 4), dim3(32, 8), 0, stream>>>(wq, wk, wv, wo, wqkvT, woutT);
  rmsnorm_score_kernel<<<dim3(S_LEN), dim3(256), 0, stream>>>(x, nw, sw, sb, h, scores);
  topk_init_kernel<<<dim3(S_LEN / 256), dim3(256), 0, stream>>>(cnt);
  topk_count_kernel<<<dim3(32, 8), dim3(256), 0, stream>>>(scores, cnt);
  topk_scatter_kernel<<<dim3(S_LEN / 256), dim3(256), 0, stream>>>(cnt, gidx);
  gemm_bt_kernel<0><<<dim3(64, 24), dim3(256), 0, stream>>>(h, wqkvT, qkv, nullptr, nullptr,
                                                            S_LEN, 3 * DIM, DIM);
  gather_kernel<<<dim3(GTOK), dim3(128), 0, stream>>>(qkv, gidx, kgbuf, vgbuf);
  attn_kernel<<<dim3(S_LEN / 64, NH), dim3(256), 0, stream>>>(qkv, kgbuf, vgbuf, gidx, obuf);
  gemm_bt_kernel<1><<<dim3(64, 8), dim3(256), 0, stream>>>(obuf, woutT, nullptr, out, x,
                                                           S_LEN, DIM, DIM);
}

// Round 3
// 306.291 us; speedup vs baseline: 2.2929x; 1.3719x over previous
//
#include <hip/hip_runtime.h>
#include <stdint.h>

#define S_LEN 8192
#define DIM   1024
#define NH    16
#define HD    64
#define WIN   1024
#define GTOK  256
#define QKV_STRIDE (3 * DIM)

typedef __attribute__((ext_vector_type(8))) short bf16x8;
typedef __attribute__((ext_vector_type(4))) float f32x4;
typedef __attribute__((ext_vector_type(16))) float f32x16;
typedef unsigned short u16;

__device__ __forceinline__ u16 f2bf(float f) {
  union { float f; uint32_t u; } v; v.f = f;
  uint32_t r = v.u + 0x7fffu + ((v.u >> 16) & 1u);
  return (u16)(r >> 16);
}

__device__ __forceinline__ void gload_lds16(const void* g, void* l) {
  __builtin_amdgcn_global_load_lds((const __attribute__((address_space(1))) void*)g,
                                   (__attribute__((address_space(3))) void*)l, 16, 0, 0);
}

// ---------------- RMSNorm + scorer ----------------
__global__ __launch_bounds__(256) void rmsnorm_score_kernel(
    const float* __restrict__ x, const float* __restrict__ nw,
    const float* __restrict__ sw, const float* __restrict__ sb,
    u16* __restrict__ h, float* __restrict__ scores) {
  int row = blockIdx.x, tid = threadIdx.x;
  const float4* xr = (const float4*)(x + (size_t)row * DIM);
  float4 v = xr[tid];
  float ss = v.x * v.x + v.y * v.y + v.z * v.z + v.w * v.w;
#pragma unroll
  for (int o = 32; o >= 1; o >>= 1) ss += __shfl_xor(ss, o);
  __shared__ float red[4], red2[4];
  int wv = tid >> 6;
  if ((tid & 63) == 0) red[wv] = ss;
  __syncthreads();
  ss = red[0] + red[1] + red[2] + red[3];
  float rn = rsqrtf(ss * (1.0f / DIM) + 1e-6f);
  float4 w4 = ((const float4*)nw)[tid];
  float h0 = v.x * rn * w4.x, h1 = v.y * rn * w4.y;
  float h2 = v.z * rn * w4.z, h3 = v.w * rn * w4.w;
  uint64_t pack = (uint64_t)f2bf(h0) | ((uint64_t)f2bf(h1) << 16) |
                  ((uint64_t)f2bf(h2) << 32) | ((uint64_t)f2bf(h3) << 48);
  *(uint64_t*)(h + (size_t)row * DIM + tid * 4) = pack;
  float4 s4 = ((const float4*)sw)[tid];
  float sc = h0 * s4.x + h1 * s4.y + h2 * s4.z + h3 * s4.w;
#pragma unroll
  for (int o = 32; o >= 1; o >>= 1) sc += __shfl_xor(sc, o);
  if ((tid & 63) == 0) red2[wv] = sc;
  __syncthreads();
  if (tid == 0) scores[row] = red2[0] + red2[1] + red2[2] + red2[3] + sb[0];
}

// ---------------- weight transpose + bf16 convert ----------------
__global__ __launch_bounds__(256) void transpose_w_kernel(
    const float* __restrict__ wq, const float* __restrict__ wk,
    const float* __restrict__ wv, const float* __restrict__ wo,
    u16* __restrict__ wqkvT, u16* __restrict__ woutT) {
  __shared__ float tile[32][33];
  int z = blockIdx.z;
  const float* src = (z == 0) ? wq : (z == 1) ? wk : (z == 2) ? wv : wo;
  u16* dst = (z < 3) ? (wqkvT + (size_t)z * DIM * DIM) : woutT;
  int tx = threadIdx.x, ty = threadIdx.y;  // 32 x 8
  int n0 = blockIdx.x * 32, k0 = blockIdx.y * 32;
#pragma unroll
  for (int i = 0; i < 4; i++)
    tile[ty + i * 8][tx] = src[(size_t)(k0 + ty + i * 8) * DIM + n0 + tx];
  __syncthreads();
#pragma unroll
  for (int i = 0; i < 4; i++)
    dst[(size_t)(n0 + ty + i * 8) * DIM + k0 + tx] = f2bf(tile[tx][ty + i * 8]);
}

// ---------------- exact top-G by distributed rank counting ----------------
__global__ __launch_bounds__(256) void topk_init_kernel(int* __restrict__ cnt) {
  cnt[blockIdx.x * 256 + threadIdx.x] = 0;
}

__global__ __launch_bounds__(256) void topk_count_kernel(
    const float* __restrict__ scores, int* __restrict__ cnt) {
  __shared__ float sj[1024];
  int jbase = blockIdx.y * 1024;
  for (int t = threadIdx.x; t < 1024; t += 256) sj[t] = scores[jbase + t];
  __syncthreads();
  int i = blockIdx.x * 256 + threadIdx.x;
  float my = scores[i];
  int c = 0;
  const float4* s4 = (const float4*)sj;
#pragma unroll 4
  for (int j = 0; j < 256; j++) {
    float4 v = s4[j];
    int b = jbase + j * 4;
    c += (v.x > my) || (v.x == my && (b + 0) < i);
    c += (v.y > my) || (v.y == my && (b + 1) < i);
    c += (v.z > my) || (v.z == my && (b + 2) < i);
    c += (v.w > my) || (v.w == my && (b + 3) < i);
  }
  if (c) atomicAdd(&cnt[i], c);
}

__global__ __launch_bounds__(256) void topk_scatter_kernel(
    const int* __restrict__ cnt, int* __restrict__ gidx) {
  int i = blockIdx.x * 256 + threadIdx.x;
  int c = cnt[i];
  if (c < GTOK) gidx[c] = i;
}

// ---------------- gather top-G K/V rows ----------------
__global__ __launch_bounds__(128) void gather_kernel(
    const u16* __restrict__ qkv, const int* __restrict__ gidx,
    u16* __restrict__ kg, u16* __restrict__ vg) {
  int g = blockIdx.x, t = threadIdx.x;
  size_t src = (size_t)gidx[g] * QKV_STRIDE;
  *(bf16x8*)(kg + (size_t)g * DIM + t * 8) = *(const bf16x8*)(qkv + src + DIM + t * 8);
  *(bf16x8*)(vg + (size_t)g * DIM + t * 8) = *(const bf16x8*)(qkv + src + 2 * DIM + t * 8);
}

// ---------------- GEMM: C[m][n] = sum_k A[m][k]*B[n][k] ----------------
template <int RESID>
__global__ __launch_bounds__(256) void gemm_bt_kernel(
    const u16* __restrict__ A, const u16* __restrict__ B,
    u16* __restrict__ Cb, float* __restrict__ Cf, const float* __restrict__ X,
    int M, int N, int K) {
  __shared__ u16 aT[128 * 64];
  __shared__ u16 bT[128 * 64];
  int tid = threadIdx.x;
  int wave = tid >> 6, lane = tid & 63;
  int l15 = lane & 15, l4 = lane >> 4;
  int wr = (wave >> 1) * 64, wc = (wave & 1) * 64;
  int mbase = blockIdx.x * 128, nbase = blockIdx.y * 128;
  f32x4 acc[4][4] = {};
  for (int kt = 0; kt < K; kt += 64) {
#pragma unroll
    for (int c = 0; c < 4; c++) {
      int chunk = wave * 4 + c;
      int row = chunk * 8 + (lane >> 3);
      int col = kt + (lane & 7) * 8;
      gload_lds16(A + (size_t)(mbase + row) * K + col, aT + chunk * 512);
      gload_lds16(B + (size_t)(nbase + row) * K + col, bT + chunk * 512);
    }
    __syncthreads();
#pragma unroll
    for (int kk = 0; kk < 2; kk++) {
      bf16x8 af[4], bfr[4];
#pragma unroll
      for (int i = 0; i < 4; i++) {
        af[i]  = *(const bf16x8*)(aT + (wr + i * 16 + l15) * 64 + kk * 32 + l4 * 8);
        bfr[i] = *(const bf16x8*)(bT + (wc + i * 16 + l15) * 64 + kk * 32 + l4 * 8);
      }
#pragma unroll
      for (int i = 0; i < 4; i++)
#pragma unroll
        for (int j = 0; j < 4; j++)
          acc[i][j] = __builtin_amdgcn_mfma_f32_16x16x32_bf16(af[i], bfr[j], acc[i][j], 0, 0, 0);
    }
    __syncthreads();
  }
#pragma unroll
  for (int i = 0; i < 4; i++) {
#pragma unroll
    for (int j = 0; j < 4; j++) {
#pragma unroll
      for (int r = 0; r < 4; r++) {
        int row = mbase + wr + i * 16 + l4 * 4 + r;
        int col = nbase + wc + j * 16 + l15;
        float v = acc[i][j][r];
        if (RESID) Cf[(size_t)row * N + col] = X[(size_t)row * N + col] + v;
        else       Cb[(size_t)row * N + col] = f2bf(v);
      }
    }
  }
}

// ---------------- fused flash attention v2: swapped-operand 32x32 MFMA ----------------
// Block = 4 waves x 32 queries = 128 q rows; KV tiles of 64 keys.
// S^T = mfma(K, Q): lane q = lane&31, keys in-register -> lane-local softmax.
// O^T = mfma(V^T, P): rescale + normalize lane-local. 1 barrier/tile.
__global__ __launch_bounds__(256) void attn_kernel(
    const u16* __restrict__ qkv, const u16* __restrict__ kg,
    const u16* __restrict__ vg, const int* __restrict__ gidx,
    u16* __restrict__ o) {
  __shared__ u16 vT[2][64][72];   // [buf][d][key^((d>>4)<<4)]
  __shared__ int gposLds[2][64];
  const int tid = threadIdx.x, wave = tid >> 6, lane = tid & 63;
  const int l31 = lane & 31, hi = lane >> 5;
  const int qbase = blockIdx.x * 128;
  const int wbase = qbase & ~(WIN - 1);
  const int qoff = qbase - wbase;
  const int hoff = blockIdx.y * HD;
  const int nLocal = qoff / 64 + 2;
  const int nTiles = nLocal + GTOK / 64;
  const int qrow = qbase + wave * 32 + l31;

  // Q B-fragments (persistent): lane holds Q[qrow][ks*16 + hi*8 + j]
  bf16x8 qf[4];
  {
    const u16* qptr = qkv + (size_t)qrow * QKV_STRIDE + hoff + hi * 8;
#pragma unroll
    for (int ks = 0; ks < 4; ks++) qf[ks] = *(const bf16x8*)(qptr + ks * 16);
  }

  // V staging mapping: thread covers key=skey, d = sq*16 .. +16
  const int skey = tid >> 2, sq = tid & 3;
  const int vcol = skey ^ (sq << 4);

  f32x16 acc0 = {}, acc1 = {};
  float mr = -3.0e38f, lr = 0.f;

  bf16x8 nv0, nv1;
  int ng = 0;
  {
    const u16* vs = qkv + (size_t)(wbase + skey) * QKV_STRIDE + 2 * DIM + hoff + sq * 16;
    nv0 = *(const bf16x8*)(vs);
    nv1 = *(const bf16x8*)(vs + 8);
  }

  for (int t = 0; t < nTiles; t++) {
    const int p = t & 1;
    const bool isLocal = (t < nLocal);
    const int tbase = wbase + t * 64;
    // ---- stage V^T (swizzled) + gpos ----
#pragma unroll
    for (int j = 0; j < 8; j++) vT[p][sq * 16 + j][vcol] = (u16)nv0[j];
#pragma unroll
    for (int j = 0; j < 8; j++) vT[p][sq * 16 + 8 + j][vcol] = (u16)nv1[j];
    if (!isLocal && tid < 64) gposLds[p][tid] = ng;
    // ---- prefetch tile t+1 (in flight during compute) ----
    if (t + 1 < nTiles) {
      const u16* vs;
      if (t + 1 < nLocal) {
        vs = qkv + (size_t)(wbase + (t + 1) * 64 + skey) * QKV_STRIDE + 2 * DIM + hoff + sq * 16;
      } else {
        vs = vg + (size_t)((t + 1 - nLocal) * 64 + skey) * DIM + hoff + sq * 16;
        if (tid < 64) ng = gidx[(t + 1 - nLocal) * 64 + tid];
      }
      nv0 = *(const bf16x8*)(vs);
      nv1 = *(const bf16x8*)(vs + 8);
    }
    __syncthreads();

    // fully-masked tile for this wave -> skip compute (still did staging+barrier)
    if (isLocal && tbase > qbase + wave * 32 + 31) continue;

    // ---- QK^T (swapped): S^T[key][q], K direct from global ----
    const u16* kp;
    size_t kstr;
    if (isLocal) {
      kp = qkv + (size_t)(tbase + l31) * QKV_STRIDE + DIM + hoff + hi * 8;
      kstr = (size_t)32 * QKV_STRIDE;
    } else {
      kp = kg + (size_t)((t - nLocal) * 64 + l31) * DIM + hoff + hi * 8;
      kstr = (size_t)32 * DIM;
    }
    float sv[32];
    __builtin_amdgcn_s_setprio(1);
#pragma unroll
    for (int kb = 0; kb < 2; kb++) {
      const u16* kpb = kp + kb * kstr;
      bf16x8 k0 = *(const bf16x8*)(kpb);
      bf16x8 k1 = *(const bf16x8*)(kpb + 16);
      bf16x8 k2 = *(const bf16x8*)(kpb + 32);
      bf16x8 k3 = *(const bf16x8*)(kpb + 48);
      f32x16 z = {};
      z = __builtin_amdgcn_mfma_f32_32x32x16_bf16(k0, qf[0], z, 0, 0, 0);
      z = __builtin_amdgcn_mfma_f32_32x32x16_bf16(k1, qf[1], z, 0, 0, 0);
      z = __builtin_amdgcn_mfma_f32_32x32x16_bf16(k2, qf[2], z, 0, 0, 0);
      z = __builtin_amdgcn_mfma_f32_32x32x16_bf16(k3, qf[3], z, 0, 0, 0);
#pragma unroll
      for (int r = 0; r < 16; r++) sv[kb * 16 + r] = z[r];
    }
    __builtin_amdgcn_s_setprio(0);

    // ---- mask + scale (exp2 domain) ----
    const float SC2 = 0.125f * 1.44269504088896f;
    if (isLocal) {
      if (tbase + 63 <= qbase + wave * 32) {  // fully unmasked for whole wave
#pragma unroll
        for (int i = 0; i < 32; i++) sv[i] *= SC2;
      } else {
#pragma unroll
        for (int kb = 0; kb < 2; kb++)
#pragma unroll
          for (int r = 0; r < 16; r++) {
            int kpos = tbase + kb * 32 + ((r & 3) + 8 * (r >> 2) + 4 * hi);
            int i = kb * 16 + r;
            sv[i] = (kpos <= qrow) ? sv[i] * SC2 : -3.0e38f;
          }
      }
    } else {
#pragma unroll
      for (int kb = 0; kb < 2; kb++)
#pragma unroll
        for (int r = 0; r < 16; r++) {
          int kpos = gposLds[p][kb * 32 + ((r & 3) + 8 * (r >> 2) + 4 * hi)];
          int i = kb * 16 + r;
          sv[i] = (kpos <= qrow) ? sv[i] * SC2 : -3.0e38f;
        }
    }

    // ---- lane-local online softmax (q = l31; partner holds other 32 keys) ----
    float m0 = sv[0], m1 = sv[1], m2 = sv[2], m3 = sv[3];
#pragma unroll
    for (int i = 4; i < 32; i += 4) {
      m0 = fmaxf(m0, sv[i]);     m1 = fmaxf(m1, sv[i + 1]);
      m2 = fmaxf(m2, sv[i + 2]); m3 = fmaxf(m3, sv[i + 3]);
    }
    float vmax = fmaxf(fmaxf(m0, m1), fmaxf(m2, m3));
    vmax = fmaxf(vmax, __shfl_xor(vmax, 32));
    float mn = fmaxf(mr, vmax);
    float al = exp2f(mr - mn);
    float s0 = 0.f, s1 = 0.f, s2 = 0.f, s3 = 0.f;
#pragma unroll
    for (int i = 0; i < 32; i += 4) {
      float p0 = exp2f(sv[i] - mn),     p1 = exp2f(sv[i + 1] - mn);
      float p2 = exp2f(sv[i + 2] - mn), p3 = exp2f(sv[i + 3] - mn);
      sv[i] = p0; sv[i + 1] = p1; sv[i + 2] = p2; sv[i + 3] = p3;
      s0 += p0; s1 += p1; s2 += p2; s3 += p3;
    }
    float ps = (s0 + s1) + (s2 + s3);
    ps += __shfl_xor(ps, 32);
    lr = lr * al + ps;
    mr = mn;
#pragma unroll
    for (int i = 0; i < 16; i++) { acc0[i] *= al; acc1[i] *= al; }

    // ---- build P B-fragments in-register (pack + half-swap with lane^32) ----
    bf16x8 pf[4];
#pragma unroll
    for (int q4 = 0; q4 < 4; q4++) {
      int b = q4 * 8;
      uint32_t w0 = (uint32_t)f2bf(sv[b + 0]) | ((uint32_t)f2bf(sv[b + 1]) << 16);
      uint32_t w1 = (uint32_t)f2bf(sv[b + 2]) | ((uint32_t)f2bf(sv[b + 3]) << 16);
      uint32_t w2 = (uint32_t)f2bf(sv[b + 4]) | ((uint32_t)f2bf(sv[b + 5]) << 16);
      uint32_t w3 = (uint32_t)f2bf(sv[b + 6]) | ((uint32_t)f2bf(sv[b + 7]) << 16);
      uint32_t w0s = __shfl_xor((int)w0, 32), w2s = __shfl_xor((int)w2, 32);
      uint32_t w1s = __shfl_xor((int)w1, 32), w3s = __shfl_xor((int)w3, 32);
      union { uint32_t w[4]; bf16x8 v; } u;
      u.w[0] = hi ? w2s : w0;
      u.w[1] = hi ? w3s : w1;
      u.w[2] = hi ? w2 : w0s;
      u.w[3] = hi ? w3 : w1s;
      pf[q4] = u.v;
    }

    // ---- PV: O^T[d][q] = mfma(V^T, P) ----
    __builtin_amdgcn_s_setprio(1);
#pragma unroll
    for (int dblk = 0; dblk < 2; dblk++) {
      const int swz = (dblk * 2 + (l31 >> 4)) << 4;
      const u16* vrow = &vT[p][dblk * 32 + l31][0];
      f32x16 a = dblk ? acc1 : acc0;
#pragma unroll
      for (int ksg = 0; ksg < 4; ksg++) {
        bf16x8 vf = *(const bf16x8*)(vrow + ((ksg * 16 + hi * 8) ^ swz));
        a = __builtin_amdgcn_mfma_f32_32x32x16_bf16(vf, pf[ksg], a, 0, 0, 0);
      }
      if (dblk) acc1 = a; else acc0 = a;
    }
    __builtin_amdgcn_s_setprio(0);
  }

  // ---- normalize (lane-local) + store O (4 consecutive cols packed per u64) ----
  float inv = 1.0f / lr;
#pragma unroll
  for (int dblk = 0; dblk < 2; dblk++) {
    f32x16 a = dblk ? acc1 : acc0;
#pragma unroll
    for (int g = 0; g < 4; g++) {
      uint64_t pk = (uint64_t)f2bf(a[g * 4 + 0] * inv)
                  | ((uint64_t)f2bf(a[g * 4 + 1] * inv) << 16)
                  | ((uint64_t)f2bf(a[g * 4 + 2] * inv) << 32)
                  | ((uint64_t)f2bf(a[g * 4 + 3] * inv) << 48);
      *(uint64_t*)(o + (size_t)qrow * DIM + hoff + dblk * 32 + g * 8 + 4 * hi) = pk;
    }
  }
}

// ---------------- launch ----------------
extern "C" void kernel_launch(void* const* d_in, const int* in_sizes, int n_in,
                              void* d_out, int out_size, void* d_ws, size_t ws_size,
                              hipStream_t stream) {
  const float* x  = (const float*)d_in[0];
  const float* nw = (const float*)d_in[1];
  const float* wq = (const float*)d_in[2];
  const float* wk = (const float*)d_in[3];
  const float* wv = (const float*)d_in[4];
  const float* wo = (const float*)d_in[5];
  const float* sw = (const float*)d_in[6];
  const float* sb = (const float*)d_in[7];
  float* out = (float*)d_out;

  char* ws = (char*)d_ws;
  size_t off = 0;
  auto alloc = [&](size_t b) {
    char* p = ws + off;
    off = (off + b + 255) & ~(size_t)255;
    return p;
  };
  u16*   h      = (u16*)alloc((size_t)S_LEN * DIM * 2);
  u16*   wqkvT  = (u16*)alloc((size_t)3 * DIM * DIM * 2);
  u16*   woutT  = (u16*)alloc((size_t)DIM * DIM * 2);
  u16*   qkv    = (u16*)alloc((size_t)S_LEN * 3 * DIM * 2);
  u16*   obuf   = (u16*)alloc((size_t)S_LEN * DIM * 2);
  float* scores = (float*)alloc((size_t)S_LEN * 4);
  int*   gidx   = (int*)alloc((size_t)GTOK * 4);
  int*   cnt    = (int*)alloc((size_t)S_LEN * 4);
  u16*   kgbuf  = (u16*)alloc((size_t)GTOK * DIM * 2);
  u16*   vgbuf  = (u16*)alloc((size_t)GTOK * DIM * 2);

  transpose_w_kernel<<<dim3(32, 32, 4), dim3(32, 8), 0, stream>>>(wq, wk, wv, wo, wqkvT, woutT);
  rmsnorm_score_kernel<<<dim3(S_LEN), dim3(256), 0, stream>>>(x, nw, sw, sb, h, scores);
  topk_init_kernel<<<dim3(S_LEN / 256), dim3(256), 0, stream>>>(cnt);
  topk_count_kernel<<<dim3(32, 8), dim3(256), 0, stream>>>(scores, cnt);
  topk_scatter_kernel<<<dim3(S_LEN / 256), dim3(256), 0, stream>>>(cnt, gidx);
  gemm_bt_kernel<0><<<dim3(64, 24), dim3(256), 0, stream>>>(h, wqkvT, qkv, nullptr, nullptr,
                                                            S_LEN, 3 * DIM, DIM);
  gather_kernel<<<dim3(GTOK), dim3(128), 0, stream>>>(qkv, gidx, kgbuf, vgbuf);
  attn_kernel<<<dim3(S_LEN / 128, NH), dim3(256), 0, stream>>>(qkv, kgbuf, vgbuf, gidx, obuf);
  gemm_bt_kernel<1><<<dim3(64, 8), dim3(256), 0, stream>>>(obuf, woutT, nullptr, out, x,
                                                           S_LEN, DIM, DIM);
}

// Round 4
// 269.711 us; speedup vs baseline: 2.6039x; 1.1356x over previous
//
#include <hip/hip_runtime.h>
#include <stdint.h>

#define S_LEN 8192
#define DIM   1024
#define NH    16
#define HD    64
#define WIN   1024
#define GTOK  256
#define QKV_STRIDE (3 * DIM)

typedef __attribute__((ext_vector_type(8))) short bf16x8;
typedef __attribute__((ext_vector_type(4))) float f32x4;
typedef __attribute__((ext_vector_type(16))) float f32x16;
typedef unsigned short u16;

__device__ __forceinline__ u16 f2bf(float f) {
  union { float f; uint32_t u; } v; v.f = f;
  uint32_t r = v.u + 0x7fffu + ((v.u >> 16) & 1u);
  return (u16)(r >> 16);
}
__device__ __forceinline__ float bf2f(u16 b) {
  union { uint32_t u; float f; } v; v.u = ((uint32_t)b) << 16;
  return v.f;
}

__device__ __forceinline__ void gload_lds16(const void* g, void* l) {
  __builtin_amdgcn_global_load_lds((const __attribute__((address_space(1))) void*)g,
                                   (__attribute__((address_space(3))) void*)l, 16, 0, 0);
}

// ---------------- RMSNorm + scorer ----------------
__global__ __launch_bounds__(256) void rmsnorm_score_kernel(
    const float* __restrict__ x, const float* __restrict__ nw,
    const float* __restrict__ sw, const float* __restrict__ sb,
    u16* __restrict__ h, float* __restrict__ scores) {
  int row = blockIdx.x, tid = threadIdx.x;
  const float4* xr = (const float4*)(x + (size_t)row * DIM);
  float4 v = xr[tid];
  float ss = v.x * v.x + v.y * v.y + v.z * v.z + v.w * v.w;
#pragma unroll
  for (int o = 32; o >= 1; o >>= 1) ss += __shfl_xor(ss, o);
  __shared__ float red[4], red2[4];
  int wv = tid >> 6;
  if ((tid & 63) == 0) red[wv] = ss;
  __syncthreads();
  ss = red[0] + red[1] + red[2] + red[3];
  float rn = rsqrtf(ss * (1.0f / DIM) + 1e-6f);
  float4 w4 = ((const float4*)nw)[tid];
  float h0 = v.x * rn * w4.x, h1 = v.y * rn * w4.y;
  float h2 = v.z * rn * w4.z, h3 = v.w * rn * w4.w;
  uint64_t pack = (uint64_t)f2bf(h0) | ((uint64_t)f2bf(h1) << 16) |
                  ((uint64_t)f2bf(h2) << 32) | ((uint64_t)f2bf(h3) << 48);
  *(uint64_t*)(h + (size_t)row * DIM + tid * 4) = pack;
  float4 s4 = ((const float4*)sw)[tid];
  float sc = h0 * s4.x + h1 * s4.y + h2 * s4.z + h3 * s4.w;
#pragma unroll
  for (int o = 32; o >= 1; o >>= 1) sc += __shfl_xor(sc, o);
  if ((tid & 63) == 0) red2[wv] = sc;
  __syncthreads();
  if (tid == 0) scores[row] = red2[0] + red2[1] + red2[2] + red2[3] + sb[0];
}

// ---------------- weight transpose + bf16 convert ----------------
__global__ __launch_bounds__(256) void transpose_w_kernel(
    const float* __restrict__ wq, const float* __restrict__ wk,
    const float* __restrict__ wv, const float* __restrict__ wo,
    u16* __restrict__ wqkvT, u16* __restrict__ woutT) {
  __shared__ float tile[32][33];
  int z = blockIdx.z;
  const float* src = (z == 0) ? wq : (z == 1) ? wk : (z == 2) ? wv : wo;
  u16* dst = (z < 3) ? (wqkvT + (size_t)z * DIM * DIM) : woutT;
  int tx = threadIdx.x, ty = threadIdx.y;  // 32 x 8
  int n0 = blockIdx.x * 32, k0 = blockIdx.y * 32;
#pragma unroll
  for (int i = 0; i < 4; i++)
    tile[ty + i * 8][tx] = src[(size_t)(k0 + ty + i * 8) * DIM + n0 + tx];
  __syncthreads();
#pragma unroll
  for (int i = 0; i < 4; i++)
    dst[(size_t)(n0 + ty + i * 8) * DIM + k0 + tx] = f2bf(tile[tx][ty + i * 8]);
}

// ---------------- exact top-G by distributed rank counting ----------------
__global__ __launch_bounds__(256) void topk_init_kernel(int* __restrict__ cnt) {
  cnt[blockIdx.x * 256 + threadIdx.x] = 0;
}

__global__ __launch_bounds__(256) void topk_count_kernel(
    const float* __restrict__ scores, int* __restrict__ cnt) {
  __shared__ float sj[1024];
  int jbase = blockIdx.y * 1024;
  for (int t = threadIdx.x; t < 1024; t += 256) sj[t] = scores[jbase + t];
  __syncthreads();
  int i = blockIdx.x * 256 + threadIdx.x;
  float my = scores[i];
  int c = 0;
  const float4* s4 = (const float4*)sj;
#pragma unroll 4
  for (int j = 0; j < 256; j++) {
    float4 v = s4[j];
    int b = jbase + j * 4;
    c += (v.x > my) || (v.x == my && (b + 0) < i);
    c += (v.y > my) || (v.y == my && (b + 1) < i);
    c += (v.z > my) || (v.z == my && (b + 2) < i);
    c += (v.w > my) || (v.w == my && (b + 3) < i);
  }
  if (c) atomicAdd(&cnt[i], c);
}

__global__ __launch_bounds__(256) void topk_scatter_kernel(
    const int* __restrict__ cnt, int* __restrict__ gidx) {
  int i = blockIdx.x * 256 + threadIdx.x;
  int c = cnt[i];
  if (c < GTOK) gidx[c] = i;
}

// ---------------- gather top-G K/V rows ----------------
__global__ __launch_bounds__(128) void gather_kernel(
    const u16* __restrict__ qkv, const int* __restrict__ gidx,
    u16* __restrict__ kg, u16* __restrict__ vg) {
  int g = blockIdx.x, t = threadIdx.x;
  size_t src = (size_t)gidx[g] * QKV_STRIDE;
  *(bf16x8*)(kg + (size_t)g * DIM + t * 8) = *(const bf16x8*)(qkv + src + DIM + t * 8);
  *(bf16x8*)(vg + (size_t)g * DIM + t * 8) = *(const bf16x8*)(qkv + src + 2 * DIM + t * 8);
}

// ---------------- GEMM: C[m][n] = sum_k A[m][k]*B[n][k] ----------------
template <int RESID>
__global__ __launch_bounds__(256) void gemm_bt_kernel(
    const u16* __restrict__ A, const u16* __restrict__ B,
    u16* __restrict__ Cb, float* __restrict__ Cf, const float* __restrict__ X,
    int M, int N, int K) {
  __shared__ u16 aT[128 * 64];
  __shared__ u16 bT[128 * 64];
  int tid = threadIdx.x;
  int wave = tid >> 6, lane = tid & 63;
  int l15 = lane & 15, l4 = lane >> 4;
  int wr = (wave >> 1) * 64, wc = (wave & 1) * 64;
  int mbase = blockIdx.x * 128, nbase = blockIdx.y * 128;
  f32x4 acc[4][4] = {};
  for (int kt = 0; kt < K; kt += 64) {
#pragma unroll
    for (int c = 0; c < 4; c++) {
      int chunk = wave * 4 + c;
      int row = chunk * 8 + (lane >> 3);
      int col = kt + (lane & 7) * 8;
      gload_lds16(A + (size_t)(mbase + row) * K + col, aT + chunk * 512);
      gload_lds16(B + (size_t)(nbase + row) * K + col, bT + chunk * 512);
    }
    __syncthreads();
#pragma unroll
    for (int kk = 0; kk < 2; kk++) {
      bf16x8 af[4], bfr[4];
#pragma unroll
      for (int i = 0; i < 4; i++) {
        af[i]  = *(const bf16x8*)(aT + (wr + i * 16 + l15) * 64 + kk * 32 + l4 * 8);
        bfr[i] = *(const bf16x8*)(bT + (wc + i * 16 + l15) * 64 + kk * 32 + l4 * 8);
      }
#pragma unroll
      for (int i = 0; i < 4; i++)
#pragma unroll
        for (int j = 0; j < 4; j++)
          acc[i][j] = __builtin_amdgcn_mfma_f32_16x16x32_bf16(af[i], bfr[j], acc[i][j], 0, 0, 0);
    }
    __syncthreads();
  }
#pragma unroll
  for (int i = 0; i < 4; i++) {
#pragma unroll
    for (int j = 0; j < 4; j++) {
#pragma unroll
      for (int r = 0; r < 4; r++) {
        int row = mbase + wr + i * 16 + l4 * 4 + r;
        int col = nbase + wc + j * 16 + l15;
        float v = acc[i][j][r];
        if (RESID) Cf[(size_t)row * N + col] = X[(size_t)row * N + col] + v;
        else       Cb[(size_t)row * N + col] = f2bf(v);
      }
    }
  }
}

// ---------------- fused flash attention v3: K staged in LDS (coalesced), swapped 32x32 MFMA ----
// Block = 4 waves x 32 queries = 128 q rows; KV tiles of 64 keys.
// S^T = mfma(K, Q): lane q = lane&31 -> lane-local softmax.
// O^T = mfma(V^T, P): rescale + normalize lane-local. 1 barrier/tile.
__global__ __launch_bounds__(256) void attn_kernel(
    const u16* __restrict__ qkv, const u16* __restrict__ kg,
    const u16* __restrict__ vg, const int* __restrict__ gidx,
    u16* __restrict__ o) {
  __shared__ u16 kT[2][64][72];   // [buf][key][d] (+8 pad)
  __shared__ u16 vT[2][64][72];   // [buf][d][key^((d>>4)<<4)]
  __shared__ int gposLds[2][64];
  const int tid = threadIdx.x, wave = tid >> 6, lane = tid & 63;
  const int l31 = lane & 31, hi = lane >> 5;
  const int qblk = (int)gridDim.x - 1 - (int)blockIdx.x;  // longest blocks first
  const int qbase = qblk * 128;
  const int wbase = qbase & ~(WIN - 1);
  const int qoff = qbase - wbase;
  const int hoff = blockIdx.y * HD;
  const int nLocal = qoff / 64 + 2;
  const int nTiles = nLocal + GTOK / 64;
  const int qrow = qbase + wave * 32 + l31;

  // Q B-fragments, with scale*log2e folded in (fp32 mul, repack to bf16)
  bf16x8 qf[4];
  {
    const float SC2 = 0.125f * 1.44269504088896f;
    const u16* qptr = qkv + (size_t)qrow * QKV_STRIDE + hoff + hi * 8;
#pragma unroll
    for (int ks = 0; ks < 4; ks++) {
      bf16x8 raw = *(const bf16x8*)(qptr + ks * 16);
      bf16x8 sc;
#pragma unroll
      for (int j = 0; j < 8; j++) sc[j] = (short)f2bf(bf2f((u16)raw[j]) * SC2);
      qf[ks] = sc;
    }
  }

  // staging map: thread covers key=skey, d = sq*16 .. +16
  const int skey = tid >> 2, sq = tid & 3;
  const int vcol = skey ^ (sq << 4);

  f32x16 acc0 = {}, acc1 = {};
  float mr = -3.0e38f, lr = 0.f;

  bf16x8 nk0, nk1, nv0, nv1;
  int ng = 0;
  {
    const u16* base = qkv + (size_t)(wbase + skey) * QKV_STRIDE + hoff + sq * 16;
    nk0 = *(const bf16x8*)(base + DIM);
    nk1 = *(const bf16x8*)(base + DIM + 8);
    nv0 = *(const bf16x8*)(base + 2 * DIM);
    nv1 = *(const bf16x8*)(base + 2 * DIM + 8);
  }

  for (int t = 0; t < nTiles; t++) {
    const int p = t & 1;
    const bool isLocal = (t < nLocal);
    const int tbase = wbase + t * 64;
    // ---- stage K (row-major) + V^T (swizzled) + gpos from prefetch regs ----
    *(bf16x8*)(&kT[p][skey][sq * 16]) = nk0;
    *(bf16x8*)(&kT[p][skey][sq * 16 + 8]) = nk1;
#pragma unroll
    for (int j = 0; j < 8; j++) vT[p][sq * 16 + j][vcol] = (u16)nv0[j];
#pragma unroll
    for (int j = 0; j < 8; j++) vT[p][sq * 16 + 8 + j][vcol] = (u16)nv1[j];
    if (!isLocal && tid < 64) gposLds[p][tid] = ng;
    // ---- prefetch tile t+1 (coalesced; in flight during compute) ----
    if (t + 1 < nTiles) {
      const u16 *ksrc, *vsrc;
      if (t + 1 < nLocal) {
        const u16* base = qkv + (size_t)(wbase + (t + 1) * 64 + skey) * QKV_STRIDE + hoff + sq * 16;
        ksrc = base + DIM;
        vsrc = base + 2 * DIM;
      } else {
        size_t grow = (size_t)((t + 1 - nLocal) * 64 + skey) * DIM + hoff + sq * 16;
        ksrc = kg + grow;
        vsrc = vg + grow;
        if (tid < 64) ng = gidx[(t + 1 - nLocal) * 64 + tid];
      }
      nk0 = *(const bf16x8*)(ksrc);
      nk1 = *(const bf16x8*)(ksrc + 8);
      nv0 = *(const bf16x8*)(vsrc);
      nv1 = *(const bf16x8*)(vsrc + 8);
    }
    __syncthreads();

    // fully-masked tile for this wave -> skip compute
    if (isLocal && tbase > qbase + wave * 32 + 31) continue;

    // ---- QK^T (swapped): S^T[key][q], K from LDS ----
    float sv[32];
    __builtin_amdgcn_s_setprio(1);
#pragma unroll
    for (int kb = 0; kb < 2; kb++) {
      const u16* krow = &kT[p][kb * 32 + l31][hi * 8];
      bf16x8 k0 = *(const bf16x8*)(krow);
      bf16x8 k1 = *(const bf16x8*)(krow + 16);
      bf16x8 k2 = *(const bf16x8*)(krow + 32);
      bf16x8 k3 = *(const bf16x8*)(krow + 48);
      f32x16 z = {};
      z = __builtin_amdgcn_mfma_f32_32x32x16_bf16(k0, qf[0], z, 0, 0, 0);
      z = __builtin_amdgcn_mfma_f32_32x32x16_bf16(k1, qf[1], z, 0, 0, 0);
      z = __builtin_amdgcn_mfma_f32_32x32x16_bf16(k2, qf[2], z, 0, 0, 0);
      z = __builtin_amdgcn_mfma_f32_32x32x16_bf16(k3, qf[3], z, 0, 0, 0);
#pragma unroll
      for (int r = 0; r < 16; r++) sv[kb * 16 + r] = z[r];
    }
    __builtin_amdgcn_s_setprio(0);

    // ---- causal mask (scale already folded into Q) ----
    if (isLocal) {
      const int lim = qrow - tbase;  // key-in-tile index must be <= lim
      if (lim < 63) {
#pragma unroll
        for (int kb = 0; kb < 2; kb++)
#pragma unroll
          for (int r = 0; r < 16; r++) {
            int crow = kb * 32 + (r & 3) + 8 * (r >> 2) + 4 * hi;
            if (crow > lim) sv[kb * 16 + r] = -3.0e38f;
          }
      }
    } else {
#pragma unroll
      for (int kb = 0; kb < 2; kb++)
#pragma unroll
        for (int r = 0; r < 16; r++) {
          int kpos = gposLds[p][kb * 32 + (r & 3) + 8 * (r >> 2) + 4 * hi];
          if (kpos > qrow) sv[kb * 16 + r] = -3.0e38f;
        }
    }

    // ---- lane-local online softmax (q = l31; partner lane^32 holds other 32 keys) ----
    float m0 = sv[0], m1 = sv[1], m2 = sv[2], m3 = sv[3];
#pragma unroll
    for (int i = 4; i < 32; i += 4) {
      m0 = fmaxf(m0, sv[i]);     m1 = fmaxf(m1, sv[i + 1]);
      m2 = fmaxf(m2, sv[i + 2]); m3 = fmaxf(m3, sv[i + 3]);
    }
    float vmax = fmaxf(fmaxf(m0, m1), fmaxf(m2, m3));
    vmax = fmaxf(vmax, __shfl_xor(vmax, 32));
    float mn = fmaxf(mr, vmax);
    float al = exp2f(mr - mn);
    float s0 = 0.f, s1 = 0.f, s2 = 0.f, s3 = 0.f;
#pragma unroll
    for (int i = 0; i < 32; i += 4) {
      float p0 = exp2f(sv[i] - mn),     p1 = exp2f(sv[i + 1] - mn);
      float p2 = exp2f(sv[i + 2] - mn), p3 = exp2f(sv[i + 3] - mn);
      sv[i] = p0; sv[i + 1] = p1; sv[i + 2] = p2; sv[i + 3] = p3;
      s0 += p0; s1 += p1; s2 += p2; s3 += p3;
    }
    float ps = (s0 + s1) + (s2 + s3);
    ps += __shfl_xor(ps, 32);
    lr = lr * al + ps;
    mr = mn;
#pragma unroll
    for (int i = 0; i < 16; i++) { acc0[i] *= al; acc1[i] *= al; }

    // ---- build P B-fragments in-register (pack + half-swap with lane^32) ----
    bf16x8 pf[4];
#pragma unroll
    for (int q4 = 0; q4 < 4; q4++) {
      int b = q4 * 8;
      uint32_t w0 = (uint32_t)f2bf(sv[b + 0]) | ((uint32_t)f2bf(sv[b + 1]) << 16);
      uint32_t w1 = (uint32_t)f2bf(sv[b + 2]) | ((uint32_t)f2bf(sv[b + 3]) << 16);
      uint32_t w2 = (uint32_t)f2bf(sv[b + 4]) | ((uint32_t)f2bf(sv[b + 5]) << 16);
      uint32_t w3 = (uint32_t)f2bf(sv[b + 6]) | ((uint32_t)f2bf(sv[b + 7]) << 16);
      uint32_t w0s = __shfl_xor((int)w0, 32), w2s = __shfl_xor((int)w2, 32);
      uint32_t w1s = __shfl_xor((int)w1, 32), w3s = __shfl_xor((int)w3, 32);
      union { uint32_t w[4]; bf16x8 v; } u;
      u.w[0] = hi ? w2s : w0;
      u.w[1] = hi ? w3s : w1;
      u.w[2] = hi ? w2 : w0s;
      u.w[3] = hi ? w3 : w1s;
      pf[q4] = u.v;
    }

    // ---- PV: O^T[d][q] = mfma(V^T, P) ----
    __builtin_amdgcn_s_setprio(1);
#pragma unroll
    for (int dblk = 0; dblk < 2; dblk++) {
      const int swz = (dblk * 2 + (l31 >> 4)) << 4;
      const u16* vrow = &vT[p][dblk * 32 + l31][0];
      f32x16 a = dblk ? acc1 : acc0;
#pragma unroll
      for (int ksg = 0; ksg < 4; ksg++) {
        bf16x8 vf = *(const bf16x8*)(vrow + ((ksg * 16 + hi * 8) ^ swz));
        a = __builtin_amdgcn_mfma_f32_32x32x16_bf16(vf, pf[ksg], a, 0, 0, 0);
      }
      if (dblk) acc1 = a; else acc0 = a;
    }
    __builtin_amdgcn_s_setprio(0);
  }

  // ---- normalize (lane-local) + store O ----
  float inv = 1.0f / lr;
#pragma unroll
  for (int dblk = 0; dblk < 2; dblk++) {
    f32x16 a = dblk ? acc1 : acc0;
#pragma unroll
    for (int g = 0; g < 4; g++) {
      uint64_t pk = (uint64_t)f2bf(a[g * 4 + 0] * inv)
                  | ((uint64_t)f2bf(a[g * 4 + 1] * inv) << 16)
                  | ((uint64_t)f2bf(a[g * 4 + 2] * inv) << 32)
                  | ((uint64_t)f2bf(a[g * 4 + 3] * inv) << 48);
      *(uint64_t*)(o + (size_t)qrow * DIM + hoff + dblk * 32 + g * 8 + 4 * hi) = pk;
    }
  }
}

// ---------------- launch ----------------
extern "C" void kernel_launch(void* const* d_in, const int* in_sizes, int n_in,
                              void* d_out, int out_size, void* d_ws, size_t ws_size,
                              hipStream_t stream) {
  const float* x  = (const float*)d_in[0];
  const float* nw = (const float*)d_in[1];
  const float* wq = (const float*)d_in[2];
  const float* wk = (const float*)d_in[3];
  const float* wv = (const float*)d_in[4];
  const float* wo = (const float*)d_in[5];
  const float* sw = (const float*)d_in[6];
  const float* sb = (const float*)d_in[7];
  float* out = (float*)d_out;

  char* ws = (char*)d_ws;
  size_t off = 0;
  auto alloc = [&](size_t b) {
    char* p = ws + off;
    off = (off + b + 255) & ~(size_t)255;
    return p;
  };
  u16*   h      = (u16*)alloc((size_t)S_LEN * DIM * 2);
  u16*   wqkvT  = (u16*)alloc((size_t)3 * DIM * DIM * 2);
  u16*   woutT  = (u16*)alloc((size_t)DIM * DIM * 2);
  u16*   qkv    = (u16*)alloc((size_t)S_LEN * 3 * DIM * 2);
  u16*   obuf   = (u16*)alloc((size_t)S_LEN * DIM * 2);
  float* scores = (float*)alloc((size_t)S_LEN * 4);
  int*   gidx   = (int*)alloc((size_t)GTOK * 4);
  int*   cnt    = (int*)alloc((size_t)S_LEN * 4);
  u16*   kgbuf  = (u16*)alloc((size_t)GTOK * DIM * 2);
  u16*   vgbuf  = (u16*)alloc((size_t)GTOK * DIM * 2);

  transpose_w_kernel<<<dim3(32, 32, 4), dim3(32, 8), 0, stream>>>(wq, wk, wv, wo, wqkvT, woutT);
  rmsnorm_score_kernel<<<dim3(S_LEN), dim3(256), 0, stream>>>(x, nw, sw, sb, h, scores);
  topk_init_kernel<<<dim3(S_LEN / 256), dim3(256), 0, stream>>>(cnt);
  topk_count_kernel<<<dim3(32, 8), dim3(256), 0, stream>>>(scores, cnt);
  topk_scatter_kernel<<<dim3(S_LEN / 256), dim3(256), 0, stream>>>(cnt, gidx);
  gemm_bt_kernel<0><<<dim3(64, 24), dim3(256), 0, stream>>>(h, wqkvT, qkv, nullptr, nullptr,
                                                            S_LEN, 3 * DIM, DIM);
  gather_kernel<<<dim3(GTOK), dim3(128), 0, stream>>>(qkv, gidx, kgbuf, vgbuf);
  attn_kernel<<<dim3(S_LEN / 128, NH), dim3(256), 0, stream>>>(qkv, kgbuf, vgbuf, gidx, obuf);
  gemm_bt_kernel<1><<<dim3(64, 8), dim3(256), 0, stream>>>(obuf, woutT, nullptr, out, x,
                                                           S_LEN, DIM, DIM);
}

// Round 5
// 230.177 us; speedup vs baseline: 3.0511x; 1.1718x over previous
//
#include <hip/hip_runtime.h>
#include <stdint.h>

#define S_LEN 8192
#define DIM   1024
#define NH    16
#define HD    64
#define WIN   1024
#define GTOK  256
#define QKV_STRIDE (3 * DIM)

typedef __attribute__((ext_vector_type(8))) short bf16x8;
typedef __attribute__((ext_vector_type(4))) float f32x4;
typedef __attribute__((ext_vector_type(16))) float f32x16;
typedef unsigned short u16;

__device__ __forceinline__ u16 f2bf(float f) {
  union { float f; uint32_t u; } v; v.f = f;
  uint32_t r = v.u + 0x7fffu + ((v.u >> 16) & 1u);
  return (u16)(r >> 16);
}
__device__ __forceinline__ float bf2f(u16 b) {
  union { uint32_t u; float f; } v; v.u = ((uint32_t)b) << 16;
  return v.f;
}
__device__ __forceinline__ uint32_t cvtpk(float a, float b) {
  uint32_t r;
  asm("v_cvt_pk_bf16_f32 %0, %1, %2" : "=v"(r) : "v"(a), "v"(b));
  return r;  // low16 = bf16(a), high16 = bf16(b)
}

__device__ __forceinline__ void gload_lds16(const void* g, void* l) {
  __builtin_amdgcn_global_load_lds((const __attribute__((address_space(1))) void*)g,
                                   (__attribute__((address_space(3))) void*)l, 16, 0, 0);
}

// ---------------- RMSNorm + scorer ----------------
__global__ __launch_bounds__(256) void rmsnorm_score_kernel(
    const float* __restrict__ x, const float* __restrict__ nw,
    const float* __restrict__ sw, const float* __restrict__ sb,
    u16* __restrict__ h, float* __restrict__ scores) {
  int row = blockIdx.x, tid = threadIdx.x;
  const float4* xr = (const float4*)(x + (size_t)row * DIM);
  float4 v = xr[tid];
  float ss = v.x * v.x + v.y * v.y + v.z * v.z + v.w * v.w;
#pragma unroll
  for (int o = 32; o >= 1; o >>= 1) ss += __shfl_xor(ss, o);
  __shared__ float red[4], red2[4];
  int wv = tid >> 6;
  if ((tid & 63) == 0) red[wv] = ss;
  __syncthreads();
  ss = red[0] + red[1] + red[2] + red[3];
  float rn = rsqrtf(ss * (1.0f / DIM) + 1e-6f);
  float4 w4 = ((const float4*)nw)[tid];
  float h0 = v.x * rn * w4.x, h1 = v.y * rn * w4.y;
  float h2 = v.z * rn * w4.z, h3 = v.w * rn * w4.w;
  uint64_t pack = (uint64_t)f2bf(h0) | ((uint64_t)f2bf(h1) << 16) |
                  ((uint64_t)f2bf(h2) << 32) | ((uint64_t)f2bf(h3) << 48);
  *(uint64_t*)(h + (size_t)row * DIM + tid * 4) = pack;
  float4 s4 = ((const float4*)sw)[tid];
  float sc = h0 * s4.x + h1 * s4.y + h2 * s4.z + h3 * s4.w;
#pragma unroll
  for (int o = 32; o >= 1; o >>= 1) sc += __shfl_xor(sc, o);
  if ((tid & 63) == 0) red2[wv] = sc;
  __syncthreads();
  if (tid == 0) scores[row] = red2[0] + red2[1] + red2[2] + red2[3] + sb[0];
}

// ---------------- weight transpose + bf16 convert ----------------
__global__ __launch_bounds__(256) void transpose_w_kernel(
    const float* __restrict__ wq, const float* __restrict__ wk,
    const float* __restrict__ wv, const float* __restrict__ wo,
    u16* __restrict__ wqkvT, u16* __restrict__ woutT) {
  __shared__ float tile[32][33];
  int z = blockIdx.z;
  const float* src = (z == 0) ? wq : (z == 1) ? wk : (z == 2) ? wv : wo;
  u16* dst = (z < 3) ? (wqkvT + (size_t)z * DIM * DIM) : woutT;
  int tx = threadIdx.x, ty = threadIdx.y;  // 32 x 8
  int n0 = blockIdx.x * 32, k0 = blockIdx.y * 32;
#pragma unroll
  for (int i = 0; i < 4; i++)
    tile[ty + i * 8][tx] = src[(size_t)(k0 + ty + i * 8) * DIM + n0 + tx];
  __syncthreads();
#pragma unroll
  for (int i = 0; i < 4; i++)
    dst[(size_t)(n0 + ty + i * 8) * DIM + k0 + tx] = f2bf(tile[tx][ty + i * 8]);
}

// ---------------- exact top-G by distributed rank counting ----------------
__global__ __launch_bounds__(256) void topk_init_kernel(int* __restrict__ cnt) {
  cnt[blockIdx.x * 256 + threadIdx.x] = 0;
}

__global__ __launch_bounds__(256) void topk_count_kernel(
    const float* __restrict__ scores, int* __restrict__ cnt) {
  __shared__ float sj[1024];
  int jbase = blockIdx.y * 1024;
  for (int t = threadIdx.x; t < 1024; t += 256) sj[t] = scores[jbase + t];
  __syncthreads();
  int i = blockIdx.x * 256 + threadIdx.x;
  float my = scores[i];
  int c = 0;
  const float4* s4 = (const float4*)sj;
#pragma unroll 4
  for (int j = 0; j < 256; j++) {
    float4 v = s4[j];
    int b = jbase + j * 4;
    c += (v.x > my) || (v.x == my && (b + 0) < i);
    c += (v.y > my) || (v.y == my && (b + 1) < i);
    c += (v.z > my) || (v.z == my && (b + 2) < i);
    c += (v.w > my) || (v.w == my && (b + 3) < i);
  }
  if (c) atomicAdd(&cnt[i], c);
}

__global__ __launch_bounds__(256) void topk_scatter_kernel(
    const int* __restrict__ cnt, int* __restrict__ gidx) {
  int i = blockIdx.x * 256 + threadIdx.x;
  int c = cnt[i];
  if (c < GTOK) gidx[c] = i;
}

// ---------------- gather top-G K/V rows ----------------
__global__ __launch_bounds__(128) void gather_kernel(
    const u16* __restrict__ qkv, const int* __restrict__ gidx,
    u16* __restrict__ kg, u16* __restrict__ vg) {
  int g = blockIdx.x, t = threadIdx.x;
  size_t src = (size_t)gidx[g] * QKV_STRIDE;
  *(bf16x8*)(kg + (size_t)g * DIM + t * 8) = *(const bf16x8*)(qkv + src + DIM + t * 8);
  *(bf16x8*)(vg + (size_t)g * DIM + t * 8) = *(const bf16x8*)(qkv + src + 2 * DIM + t * 8);
}

// ---------------- GEMM: C[m][n] = sum_k A[m][k]*B[n][k] ----------------
template <int RESID>
__global__ __launch_bounds__(256) void gemm_bt_kernel(
    const u16* __restrict__ A, const u16* __restrict__ B,
    u16* __restrict__ Cb, float* __restrict__ Cf, const float* __restrict__ X,
    int M, int N, int K) {
  __shared__ u16 aT[128 * 64];
  __shared__ u16 bT[128 * 64];
  int tid = threadIdx.x;
  int wave = tid >> 6, lane = tid & 63;
  int l15 = lane & 15, l4 = lane >> 4;
  int wr = (wave >> 1) * 64, wc = (wave & 1) * 64;
  int mbase = blockIdx.x * 128, nbase = blockIdx.y * 128;
  f32x4 acc[4][4] = {};
  for (int kt = 0; kt < K; kt += 64) {
#pragma unroll
    for (int c = 0; c < 4; c++) {
      int chunk = wave * 4 + c;
      int row = chunk * 8 + (lane >> 3);
      int col = kt + (lane & 7) * 8;
      gload_lds16(A + (size_t)(mbase + row) * K + col, aT + chunk * 512);
      gload_lds16(B + (size_t)(nbase + row) * K + col, bT + chunk * 512);
    }
    __syncthreads();
#pragma unroll
    for (int kk = 0; kk < 2; kk++) {
      bf16x8 af[4], bfr[4];
#pragma unroll
      for (int i = 0; i < 4; i++) {
        af[i]  = *(const bf16x8*)(aT + (wr + i * 16 + l15) * 64 + kk * 32 + l4 * 8);
        bfr[i] = *(const bf16x8*)(bT + (wc + i * 16 + l15) * 64 + kk * 32 + l4 * 8);
      }
#pragma unroll
      for (int i = 0; i < 4; i++)
#pragma unroll
        for (int j = 0; j < 4; j++)
          acc[i][j] = __builtin_amdgcn_mfma_f32_16x16x32_bf16(af[i], bfr[j], acc[i][j], 0, 0, 0);
    }
    __syncthreads();
  }
#pragma unroll
  for (int i = 0; i < 4; i++) {
#pragma unroll
    for (int j = 0; j < 4; j++) {
#pragma unroll
      for (int r = 0; r < 4; r++) {
        int row = mbase + wr + i * 16 + l4 * 4 + r;
        int col = nbase + wc + j * 16 + l15;
        float v = acc[i][j][r];
        if (RESID) Cf[(size_t)row * N + col] = X[(size_t)row * N + col] + v;
        else       Cb[(size_t)row * N + col] = f2bf(v);
      }
    }
  }
}

// ---------------- fused flash attention v4: 8 waves, paired 256-q supertiles ----------------
// Block = 8 waves x 32 q = 256 q supertile; processes supertiles {pair, 3-pair} of its
// window sequentially -> every block does exactly 20 local + 8 global = 28 KV tiles.
// S^T = mfma(K, Q): lane q = lane&31 -> lane-local softmax (defer-max, cvt_pk pack).
// O^T = mfma(V^T, P). 1 barrier/tile, double-buffered LDS, reg-prefetch chained
// across the supertile boundary (B's tile0 == window tile0).
__global__ __launch_bounds__(512) void attn_kernel(
    const u16* __restrict__ qkv, const u16* __restrict__ kg,
    const u16* __restrict__ vg, const int* __restrict__ gidx,
    u16* __restrict__ o) {
  __shared__ u16 kT[2][64][72];   // [buf][key][d] (+8 pad)
  __shared__ u16 vT[2][64][72];   // [buf][d][key^((d>>4)<<4)]
  __shared__ int gposLds[2][64];
  const int tid = threadIdx.x, wave = tid >> 6, lane = tid & 63;
  const int l31 = lane & 31, hi = lane >> 5;
  const int win = blockIdx.x >> 1, pair = blockIdx.x & 1;
  const int wbase = win * WIN;
  const int hoff = blockIdx.y * HD;

  // staging map: thread covers key=skey, dims sd8..sd8+7 (16 B of K and of V)
  const int skey = tid >> 3, sd8 = (tid & 7) * 8;
  const int vcol = skey ^ ((sd8 >> 4) << 4);

  // prologue prefetch: window tile 0 (shared by both supertiles' t=0)
  bf16x8 nk, nv;
  int ng = 0;
  {
    const u16* base = qkv + (size_t)(wbase + skey) * QKV_STRIDE + hoff + sd8;
    nk = *(const bf16x8*)(base + DIM);
    nv = *(const bf16x8*)(base + 2 * DIM);
  }

  for (int sp = 0; sp < 2; sp++) {
    const int j = sp ? (3 - pair) : pair;          // supertile index in window
    const int qsbase = wbase + j * 256;
    const int nLocal = (j + 1) * 4;
    const int nTiles = nLocal + GTOK / 64;
    const int qrow = qsbase + wave * 32 + l31;
    const int qwmax = qsbase + wave * 32 + 31;

    // Q B-fragments with scale*log2e folded in
    bf16x8 qf[4];
    {
      const float SC2 = 0.125f * 1.44269504088896f;
      const u16* qptr = qkv + (size_t)qrow * QKV_STRIDE + hoff + hi * 8;
#pragma unroll
      for (int ks = 0; ks < 4; ks++) {
        bf16x8 raw = *(const bf16x8*)(qptr + ks * 16);
        bf16x8 sc;
#pragma unroll
        for (int jj = 0; jj < 8; jj++) sc[jj] = (short)f2bf(bf2f((u16)raw[jj]) * SC2);
        qf[ks] = sc;
      }
    }

    f32x16 acc0 = {}, acc1 = {};
    float mr = -3.0e38f, lr = 0.f;

    __syncthreads();  // all waves done with LDS buffers from previous supertile

    for (int t = 0; t < nTiles; t++) {
      const int p = t & 1;
      const bool isLocal = (t < nLocal);
      const int tbase = wbase + t * 64;
      // ---- stage K (row-major) + V^T (swizzled) + gpos from prefetch regs ----
      *(bf16x8*)(&kT[p][skey][sd8]) = nk;
#pragma unroll
      for (int jj = 0; jj < 8; jj++) vT[p][sd8 + jj][vcol] = (u16)nv[jj];
      if (!isLocal && tid < 64) gposLds[p][tid] = ng;
      // ---- prefetch next tile (chained across supertile boundary) ----
      {
        const int nt = t + 1;
        const u16 *ksrc = nullptr, *vsrc = nullptr;
        if (nt < nLocal) {
          const u16* base = qkv + (size_t)(wbase + nt * 64 + skey) * QKV_STRIDE + hoff + sd8;
          ksrc = base + DIM; vsrc = base + 2 * DIM;
        } else if (nt < nTiles) {
          size_t grow = (size_t)((nt - nLocal) * 64 + skey) * DIM + hoff + sd8;
          ksrc = kg + grow; vsrc = vg + grow;
          if (tid < 64) ng = gidx[(nt - nLocal) * 64 + tid];
        } else if (sp == 0) {  // supertile B's tile 0 = window tile 0
          const u16* base = qkv + (size_t)(wbase + skey) * QKV_STRIDE + hoff + sd8;
          ksrc = base + DIM; vsrc = base + 2 * DIM;
        }
        if (ksrc) { nk = *(const bf16x8*)(ksrc); nv = *(const bf16x8*)(vsrc); }
      }
      __syncthreads();

      // fully-masked local tile for this wave -> skip compute
      if (isLocal && tbase > qwmax) continue;

      // ---- QK^T (swapped): S^T[key][q], K from LDS ----
      float sv[32];
      __builtin_amdgcn_s_setprio(1);
#pragma unroll
      for (int kb = 0; kb < 2; kb++) {
        const u16* krow = &kT[p][kb * 32 + l31][hi * 8];
        bf16x8 k0 = *(const bf16x8*)(krow);
        bf16x8 k1 = *(const bf16x8*)(krow + 16);
        bf16x8 k2 = *(const bf16x8*)(krow + 32);
        bf16x8 k3 = *(const bf16x8*)(krow + 48);
        f32x16 z = {};
        z = __builtin_amdgcn_mfma_f32_32x32x16_bf16(k0, qf[0], z, 0, 0, 0);
        z = __builtin_amdgcn_mfma_f32_32x32x16_bf16(k1, qf[1], z, 0, 0, 0);
        z = __builtin_amdgcn_mfma_f32_32x32x16_bf16(k2, qf[2], z, 0, 0, 0);
        z = __builtin_amdgcn_mfma_f32_32x32x16_bf16(k3, qf[3], z, 0, 0, 0);
#pragma unroll
        for (int r = 0; r < 16; r++) sv[kb * 16 + r] = z[r];
      }
      __builtin_amdgcn_s_setprio(0);

      // ---- causal mask (scale already folded into Q) ----
      if (isLocal) {
        const int lim = qrow - tbase;
        if (lim < 63) {
#pragma unroll
          for (int kb = 0; kb < 2; kb++)
#pragma unroll
            for (int r = 0; r < 16; r++) {
              int crow = kb * 32 + (r & 3) + 8 * (r >> 2) + 4 * hi;
              if (crow > lim) sv[kb * 16 + r] = -3.0e38f;
            }
        }
      } else {
#pragma unroll
        for (int kb = 0; kb < 2; kb++)
#pragma unroll
          for (int r = 0; r < 16; r++) {
            int kpos = gposLds[p][kb * 32 + (r & 3) + 8 * (r >> 2) + 4 * hi];
            if (kpos > qrow) sv[kb * 16 + r] = -3.0e38f;
          }
      }

      // ---- lane-local online softmax with defer-max (T13) ----
      float m0 = sv[0], m1 = sv[1], m2 = sv[2], m3 = sv[3];
#pragma unroll
      for (int i = 4; i < 32; i += 4) {
        m0 = fmaxf(m0, sv[i]);     m1 = fmaxf(m1, sv[i + 1]);
        m2 = fmaxf(m2, sv[i + 2]); m3 = fmaxf(m3, sv[i + 3]);
      }
      float vmax = fmaxf(fmaxf(m0, m1), fmaxf(m2, m3));
      vmax = fmaxf(vmax, __shfl_xor(vmax, 32));
      if (__any(vmax > mr + 11.0f)) {     // rescale path
        float mn = fmaxf(mr, vmax);
        float al = exp2f(mr - mn);
        lr *= al;
        mr = mn;
#pragma unroll
        for (int i = 0; i < 16; i++) { acc0[i] *= al; acc1[i] *= al; }
      }
      float s0 = 0.f, s1 = 0.f, s2 = 0.f, s3 = 0.f;
#pragma unroll
      for (int i = 0; i < 32; i += 4) {
        float p0 = exp2f(sv[i] - mr),     p1 = exp2f(sv[i + 1] - mr);
        float p2 = exp2f(sv[i + 2] - mr), p3 = exp2f(sv[i + 3] - mr);
        sv[i] = p0; sv[i + 1] = p1; sv[i + 2] = p2; sv[i + 3] = p3;
        s0 += p0; s1 += p1; s2 += p2; s3 += p3;
      }
      float ps = (s0 + s1) + (s2 + s3);
      ps += __shfl_xor(ps, 32);
      lr += ps;

      // ---- build P B-fragments in-register (cvt_pk + half-swap with lane^32) ----
      bf16x8 pf[4];
#pragma unroll
      for (int q4 = 0; q4 < 4; q4++) {
        int b = q4 * 8;
        uint32_t w0 = cvtpk(sv[b + 0], sv[b + 1]);
        uint32_t w1 = cvtpk(sv[b + 2], sv[b + 3]);
        uint32_t w2 = cvtpk(sv[b + 4], sv[b + 5]);
        uint32_t w3 = cvtpk(sv[b + 6], sv[b + 7]);
        uint32_t w0s = __shfl_xor((int)w0, 32), w2s = __shfl_xor((int)w2, 32);
        uint32_t w1s = __shfl_xor((int)w1, 32), w3s = __shfl_xor((int)w3, 32);
        union { uint32_t w[4]; bf16x8 v; } u;
        u.w[0] = hi ? w2s : w0;
        u.w[1] = hi ? w3s : w1;
        u.w[2] = hi ? w2 : w0s;
        u.w[3] = hi ? w3 : w1s;
        pf[q4] = u.v;
      }

      // ---- PV: O^T[d][q] = mfma(V^T, P) ----
      __builtin_amdgcn_s_setprio(1);
#pragma unroll
      for (int dblk = 0; dblk < 2; dblk++) {
        const int swz = (dblk * 2 + (l31 >> 4)) << 4;
        const u16* vrow = &vT[p][dblk * 32 + l31][0];
        f32x16 a = dblk ? acc1 : acc0;
#pragma unroll
        for (int ksg = 0; ksg < 4; ksg++) {
          bf16x8 vf = *(const bf16x8*)(vrow + ((ksg * 16 + hi * 8) ^ swz));
          a = __builtin_amdgcn_mfma_f32_32x32x16_bf16(vf, pf[ksg], a, 0, 0, 0);
        }
        if (dblk) acc1 = a; else acc0 = a;
      }
      __builtin_amdgcn_s_setprio(0);
    }

    // ---- normalize (lane-local) + store O for this supertile ----
    float inv = 1.0f / lr;
#pragma unroll
    for (int dblk = 0; dblk < 2; dblk++) {
      f32x16 a = dblk ? acc1 : acc0;
#pragma unroll
      for (int g = 0; g < 4; g++) {
        uint64_t pk = (uint64_t)f2bf(a[g * 4 + 0] * inv)
                    | ((uint64_t)f2bf(a[g * 4 + 1] * inv) << 16)
                    | ((uint64_t)f2bf(a[g * 4 + 2] * inv) << 32)
                    | ((uint64_t)f2bf(a[g * 4 + 3] * inv) << 48);
        *(uint64_t*)(o + (size_t)qrow * DIM + hoff + dblk * 32 + g * 8 + 4 * hi) = pk;
      }
    }
  }
}

// ---------------- launch ----------------
extern "C" void kernel_launch(void* const* d_in, const int* in_sizes, int n_in,
                              void* d_out, int out_size, void* d_ws, size_t ws_size,
                              hipStream_t stream) {
  const float* x  = (const float*)d_in[0];
  const float* nw = (const float*)d_in[1];
  const float* wq = (const float*)d_in[2];
  const float* wk = (const float*)d_in[3];
  const float* wv = (const float*)d_in[4];
  const float* wo = (const float*)d_in[5];
  const float* sw = (const float*)d_in[6];
  const float* sb = (const float*)d_in[7];
  float* out = (float*)d_out;

  char* ws = (char*)d_ws;
  size_t off = 0;
  auto alloc = [&](size_t b) {
    char* p = ws + off;
    off = (off + b + 255) & ~(size_t)255;
    return p;
  };
  u16*   h      = (u16*)alloc((size_t)S_LEN * DIM * 2);
  u16*   wqkvT  = (u16*)alloc((size_t)3 * DIM * DIM * 2);
  u16*   woutT  = (u16*)alloc((size_t)DIM * DIM * 2);
  u16*   qkv    = (u16*)alloc((size_t)S_LEN * 3 * DIM * 2);
  u16*   obuf   = (u16*)alloc((size_t)S_LEN * DIM * 2);
  float* scores = (float*)alloc((size_t)S_LEN * 4);
  int*   gidx   = (int*)alloc((size_t)GTOK * 4);
  int*   cnt    = (int*)alloc((size_t)S_LEN * 4);
  u16*   kgbuf  = (u16*)alloc((size_t)GTOK * DIM * 2);
  u16*   vgbuf  = (u16*)alloc((size_t)GTOK * DIM * 2);

  transpose_w_kernel<<<dim3(32, 32, 4), dim3(32, 8), 0, stream>>>(wq, wk, wv, wo, wqkvT, woutT);
  rmsnorm_score_kernel<<<dim3(S_LEN), dim3(256), 0, stream>>>(x, nw, sw, sb, h, scores);
  topk_init_kernel<<<dim3(S_LEN / 256), dim3(256), 0, stream>>>(cnt);
  topk_count_kernel<<<dim3(32, 8), dim3(256), 0, stream>>>(scores, cnt);
  topk_scatter_kernel<<<dim3(S_LEN / 256), dim3(256), 0, stream>>>(cnt, gidx);
  gemm_bt_kernel<0><<<dim3(64, 24), dim3(256), 0, stream>>>(h, wqkvT, qkv, nullptr, nullptr,
                                                            S_LEN, 3 * DIM, DIM);
  gather_kernel<<<dim3(GTOK), dim3(128), 0, stream>>>(qkv, gidx, kgbuf, vgbuf);
  attn_kernel<<<dim3(16, NH), dim3(512), 0, stream>>>(qkv, kgbuf, vgbuf, gidx, obuf);
  gemm_bt_kernel<1><<<dim3(64, 8), dim3(256), 0, stream>>>(obuf, woutT, nullptr, out, x,
                                                           S_LEN, DIM, DIM);
}